// Round 9
// baseline (1014.694 us; speedup 1.0000x reference)
//
#include <hip/hip_runtime.h>
#include <hip/hip_fp16.h>

#define B_ 4
#define N_ 1024

typedef __attribute__((ext_vector_type(8))) short short8;
typedef __attribute__((ext_vector_type(4))) float f32x4;
typedef __attribute__((ext_vector_type(4))) unsigned short us4;

static __device__ __forceinline__ unsigned short f2bf(float x) {
    union { float f; unsigned u; } v; v.f = x;
    unsigned r = v.u + 0x7FFFu + ((v.u >> 16) & 1u);
    return (unsigned short)(r >> 16);
}
static __device__ __forceinline__ float bf2f(unsigned short u) {
    union { unsigned x; float f; } v; v.x = (unsigned)u << 16; return v.f;
}
static __device__ __forceinline__ unsigned short f2h(float x) {
    __half h = __float2half(x); return __half_as_ushort(h);
}
static __device__ __forceinline__ float h2f(unsigned short u) {
    return __half2float(__ushort_as_half(u));
}

// ---------------- LayerNorm over 256 (one wave per row), bf16 out ----------
__global__ __launch_bounds__(256) void ln256_kernel(
    const float* __restrict__ x, const float* __restrict__ g,
    const float* __restrict__ bta, unsigned short* __restrict__ out)
{
    int row = blockIdx.x * 4 + (threadIdx.x >> 6);
    int lane = threadIdx.x & 63;
    const float4 v = *(const float4*)(x + (size_t)row * 256 + lane * 4);
    float s1 = v.x + v.y + v.z + v.w;
    float s2 = v.x * v.x + v.y * v.y + v.z * v.z + v.w * v.w;
#pragma unroll
    for (int m = 1; m < 64; m <<= 1) {
        s1 += __shfl_xor(s1, m, 64);
        s2 += __shfl_xor(s2, m, 64);
    }
    float mu = s1 * (1.f / 256.f);
    float var = s2 * (1.f / 256.f) - mu * mu;
    float rs = rsqrtf(var + 1e-5f);
    const float4 gv = *(const float4*)(g + lane * 4);
    const float4 bv = *(const float4*)(bta + lane * 4);
    us4 o;
    o[0] = f2bf((v.x - mu) * rs * gv.x + bv.x);
    o[1] = f2bf((v.y - mu) * rs * gv.y + bv.y);
    o[2] = f2bf((v.z - mu) * rs * gv.z + bv.z);
    o[3] = f2bf((v.w - mu) * rs * gv.w + bv.w);
    *(us4*)(out + (size_t)row * 256 + lane * 4) = o;
}

// ------ repack bf16 qkv [bn][(sd)*16+h] -> qkvT [bn][h][sd], vT [b][h][k][n]
__global__ __launch_bounds__(256) void repack_kernel(
    const unsigned short* __restrict__ qkvb, unsigned short* __restrict__ qkvT,
    unsigned short* __restrict__ vT)
{
    __shared__ unsigned short ld[768];
    int bn = blockIdx.x, t = threadIdx.x;
    const unsigned short* src = qkvb + (size_t)bn * 768;
    ld[t] = src[t]; ld[t + 256] = src[t + 256]; ld[t + 512] = src[t + 512];
    __syncthreads();
    unsigned short* dst = qkvT + (size_t)bn * 768;
#pragma unroll
    for (int i = 0; i < 3; ++i) {
        int o = t + i * 256;
        int h = o / 48, sd = o - h * 48;
        dst[o] = ld[sd * 16 + h];
    }
    int b = bn >> 10, n = bn & 1023;
    int h = t >> 4, k = t & 15;
    vT[(((size_t)(b * 16 + h) * 16 + k) << 10) + n] = ld[(32 + k) * 16 + h];
}

// ---------------- generic bf16 MFMA GEMM, 64x64 tile, BK=32 ----------------
// EPI bits: 1 = ELU, 2 = residual add, 4 = bf16 output
template <int EPI>
__global__ __launch_bounds__(256) void gemm_kernel(
    const unsigned short* __restrict__ A, const float* __restrict__ Bw,
    const float* __restrict__ bias, const float* __restrict__ res,
    float* __restrict__ outf, unsigned short* __restrict__ outh,
    int M, int K, int Nn)
{
    __shared__ __align__(16) short As[64][40];
    __shared__ __align__(16) short Bs[64][40];
    int tid = threadIdx.x;
    int n0 = blockIdx.x * 64, m0 = blockIdx.y * 64;
    int lane = tid & 63, wid = tid >> 6;
    int wm = (wid >> 1) * 32, wn = (wid & 1) * 32;
    int fr = lane & 15, quad = lane >> 4;
    f32x4 acc00 = {0.f,0.f,0.f,0.f}, acc01 = {0.f,0.f,0.f,0.f};
    f32x4 acc10 = {0.f,0.f,0.f,0.f}, acc11 = {0.f,0.f,0.f,0.f};
    int ar = tid >> 2, akc = (tid & 3) * 8;
    int bk = tid >> 3, bnc = (tid & 7) * 8;
    for (int k0 = 0; k0 < K; k0 += 32) {
        *(uint4*)&As[ar][akc] = *(const uint4*)(A + (size_t)(m0 + ar) * K + k0 + akc);
        const float* bp = Bw + (size_t)(k0 + bk) * Nn + n0 + bnc;
        float4 b1 = *(const float4*)bp;
        float4 b2 = *(const float4*)(bp + 4);
        Bs[bnc + 0][bk] = (short)f2bf(b1.x);
        Bs[bnc + 1][bk] = (short)f2bf(b1.y);
        Bs[bnc + 2][bk] = (short)f2bf(b1.z);
        Bs[bnc + 3][bk] = (short)f2bf(b1.w);
        Bs[bnc + 4][bk] = (short)f2bf(b2.x);
        Bs[bnc + 5][bk] = (short)f2bf(b2.y);
        Bs[bnc + 6][bk] = (short)f2bf(b2.z);
        Bs[bnc + 7][bk] = (short)f2bf(b2.w);
        __syncthreads();
        short8 af0 = *(const short8*)&As[wm + fr][quad * 8];
        short8 af1 = *(const short8*)&As[wm + 16 + fr][quad * 8];
        short8 bf0 = *(const short8*)&Bs[wn + fr][quad * 8];
        short8 bf1 = *(const short8*)&Bs[wn + 16 + fr][quad * 8];
        acc00 = __builtin_amdgcn_mfma_f32_16x16x32_bf16(af0, bf0, acc00, 0, 0, 0);
        acc01 = __builtin_amdgcn_mfma_f32_16x16x32_bf16(af0, bf1, acc01, 0, 0, 0);
        acc10 = __builtin_amdgcn_mfma_f32_16x16x32_bf16(af1, bf0, acc10, 0, 0, 0);
        acc11 = __builtin_amdgcn_mfma_f32_16x16x32_bf16(af1, bf1, acc11, 0, 0, 0);
        __syncthreads();
    }
#pragma unroll
    for (int fm = 0; fm < 2; ++fm) {
#pragma unroll
        for (int fn = 0; fn < 2; ++fn) {
            f32x4 a = (fm == 0) ? (fn == 0 ? acc00 : acc01) : (fn == 0 ? acc10 : acc11);
#pragma unroll
            for (int r = 0; r < 4; ++r) {
                int row = m0 + wm + fm * 16 + quad * 4 + r;
                int col = n0 + wn + fn * 16 + fr;
                float v = a[r] + bias[col];
                if (EPI & 2) v += res[(size_t)row * Nn + col];
                if (EPI & 1) v = v > 0.f ? v : __expf(v) - 1.f;
                if (EPI & 4) outh[(size_t)row * Nn + col] = f2bf(v);
                else         outf[(size_t)row * Nn + col] = v;
            }
        }
    }
}

// ---- finalize: sum m-half partials -> vattn (bf16), dbuf (invd) ----
__global__ __launch_bounds__(256) void finalize_kernel(
    const float* __restrict__ pacc, const float* __restrict__ pden,
    const float* __restrict__ pgs, unsigned short* __restrict__ vattn,
    float* __restrict__ dbuf)
{
    int row = blockIdx.x;            // (b*1024 + l) in [0,4096)
    int t = threadIdx.x;             // k*16 + h
    int h = t & 15;
    float a = pacc[(size_t)row * 256 + t] + pacc[1048576 + (size_t)row * 256 + t];
    float den = pden[row * 16 + h] + pden[65536 + row * 16 + h];
    float gs  = pgs[row * 16 + h]  + pgs[65536 + row * 16 + h];
    float id = 1.f / den;
    float sc = ((row & 1023) == 0) ? 1.f : log1pf(gs);
    vattn[(size_t)row * 256 + t] = f2bf(a * id * sc);
    if (t < 16) dbuf[row * 16 + t] = 1.f / (pden[row * 16 + t] + pden[65536 + row * 16 + t]);
}

// ------------------ fused edge attention, MFMA everywhere ------------------
// PASS 1: (b, 16-l tile, m half): partial den/gs/PV -> pacc/pden/pgs
// PASS 2: (b, 16-l tile, m half): recompute s, e-out + edge FFN
// wave w (of 16) owns head h = w. Chunk = 32 m columns. Both passes grid 512.
template <int PASS>
__global__ __launch_bounds__(1024, 4) void attn_kernel(
    const float* __restrict__ ef_in, float* __restrict__ ef_out,
    const unsigned short* __restrict__ qkvT, const unsigned short* __restrict__ vT,
    float* __restrict__ pacc, float* __restrict__ pden, float* __restrict__ pgs,
    const float* __restrict__ dbuf,
    const float* __restrict__ w_eb, const float* __restrict__ b_eb,
    const float* __restrict__ w_g,  const float* __restrict__ b_g,
    const float* __restrict__ ln_e_g, const float* __restrict__ ln_e_b,
    const float* __restrict__ w_eo, const float* __restrict__ b_eo,
    const float* __restrict__ effn_g, const float* __restrict__ effn_b,
    const float* __restrict__ w_e1, const float* __restrict__ b_e1,
    const float* __restrict__ w_e2, const float* __restrict__ b_e2)
{
    constexpr int ANORM_B = 512 * 24 * 2;                      // bf16, stride 24 shorts
    constexpr int EB_B    = 512 * 18 * 2;                      // f16,  stride 18 shorts
    constexpr int AUX_B   = (PASS == 1) ? 512 * 18 * 2 : 512 * 24 * 2; // gates / pmat
    // tail (P1 pvs 20480 B, P2 trs 24576 B) aliases anorm (24576 B)
    // totals: P1 61440 B, P2 67584 B -> 2 blocks/CU by LDS
    __shared__ __align__(16) char smem[ANORM_B + EB_B + AUX_B];
    unsigned short* anorm = (unsigned short*)smem;
    unsigned short* eb_l  = (unsigned short*)(smem + ANORM_B);
    unsigned short* aux   = (unsigned short*)(smem + ANORM_B + EB_B);
    unsigned short* tail  = anorm;

    const int bx = blockIdx.x;
    const int b = bx >> 7;
    const int lt = (bx >> 1) & 63;
    const int half = bx & 1;
    const int mbase = half * 512;
    const int nchunk = 16;
    const int l0 = lt * 16;
    const int tid = threadIdx.x;
    const int wv = tid >> 6;      // head h
    const int lane = tid & 63;
    const int c = lane & 15;
    const int quad = lane >> 4;
    const size_t bN = (size_t)b * 1024;

    const short8 z8 = {0,0,0,0,0,0,0,0};
    const f32x4 zf = {0.f,0.f,0.f,0.f};

    // folded biases (output channel = c)
    float beb_c = b_eb[c], bg_c = 0.f, be1_c = 0.f, beo_c = 0.f, be2_c = 0.f;
    if constexpr (PASS == 1) bg_c = b_g[c];
    if constexpr (PASS == 2) { be1_c = b_e1[c]; beo_c = b_eo[c]; be2_c = b_e2[c]; }
    for (int e = 0; e < 16; ++e) {
        float lb = ln_e_b[e];
        beb_c += lb * w_eb[e * 16 + c];
        if constexpr (PASS == 1) bg_c += lb * w_g[e * 16 + c];
        if constexpr (PASS == 2) be1_c += effn_b[e] * w_e1[e * 16 + c];
    }
    // B-fragments (K = quad*8+j, N = c)
    short8 web_f = z8, wg_f = z8, weo_f = z8, we1_f = z8, we2_f = z8;
    if (quad < 2) {
#pragma unroll
        for (int j = 0; j < 8; ++j) {
            int e = quad * 8 + j;
            web_f[j] = (short)f2bf(ln_e_g[e] * w_eb[e * 16 + c]);
            if constexpr (PASS == 1) wg_f[j] = (short)f2bf(ln_e_g[e] * w_g[e * 16 + c]);
            if constexpr (PASS == 2) {
                weo_f[j] = (short)f2bf(w_eo[e * 16 + c]);
                we1_f[j] = (short)f2bf(effn_g[e] * w_e1[e * 16 + c]);
                we2_f[j] = (short)f2bf(w_e2[e * 16 + c]);
            }
        }
    }
    // Q fragment: A[l = c][d = quad*8+j] for head wv
    short8 qf = z8;
    if (quad < 2)
        qf = *(const short8*)(qkvT + (bN + l0 + c) * 768 + wv * 48 + quad * 8);

    float invd[4];
    float den_r[4] = {0.f,0.f,0.f,0.f}, gs_r[4] = {0.f,0.f,0.f,0.f};
    f32x4 acc_pv = zf;
    float muR = 0.f, sgR = 0.f;   // this lane's stage-1 row stats (PASS 2)
    if constexpr (PASS == 2) {
#pragma unroll
        for (int r = 0; r < 4; ++r)
            invd[r] = dbuf[(bN + l0 + quad * 4 + r) * 16 + wv];
    }

    for (int ch = 0; ch < nchunk; ++ch) {
        const int m0 = mbase + ch * 32;
        // ---- stage 1: LN of efeat chunk -> anorm (row = l*32+m) ----
        {
            int row = tid >> 1, halfw = tid & 1;
            int lr = row >> 5, mr = row & 31;
            const float* ep = ef_in + ((bN + l0 + lr) * 1024 + m0 + mr) * 16 + halfw * 8;
            float4 x0 = *(const float4*)ep;
            float4 x1 = *(const float4*)(ep + 4);
            float s1 = x0.x + x0.y + x0.z + x0.w + x1.x + x1.y + x1.z + x1.w;
            float s2 = x0.x*x0.x + x0.y*x0.y + x0.z*x0.z + x0.w*x0.w
                     + x1.x*x1.x + x1.y*x1.y + x1.z*x1.z + x1.w*x1.w;
            s1 += __shfl_xor(s1, 1, 64);
            s2 += __shfl_xor(s2, 1, 64);
            float mu = s1 * (1.f / 16.f);
            float vv = s2 * (1.f / 16.f) - mu * mu + 1e-5f;
            float rs = rsqrtf(vv);
            if constexpr (PASS == 2) { muR = mu; sgR = vv * rs; }
            short8 o;
            o[0] = (short)f2bf((x0.x - mu) * rs); o[1] = (short)f2bf((x0.y - mu) * rs);
            o[2] = (short)f2bf((x0.z - mu) * rs); o[3] = (short)f2bf((x0.w - mu) * rs);
            o[4] = (short)f2bf((x1.x - mu) * rs); o[5] = (short)f2bf((x1.y - mu) * rs);
            o[6] = (short)f2bf((x1.z - mu) * rs); o[7] = (short)f2bf((x1.w - mu) * rs);
            *(short8*)(anorm + row * 24 + halfw * 8) = o;
        }
        __syncthreads();
        // ---- stage 2: e_bias (+gates) MFMA, 2 row-groups per wave ----
#pragma unroll
        for (int gg = 0; gg < 2; ++gg) {
            int g = wv * 2 + gg;
            short8 af = z8;
            if (quad < 2) af = *(const short8*)(anorm + (g * 16 + c) * 24 + quad * 8);
            f32x4 eb = __builtin_amdgcn_mfma_f32_16x16x32_bf16(af, web_f, zf, 0, 0, 0);
#pragma unroll
            for (int r = 0; r < 4; ++r)
                eb_l[(g * 16 + quad * 4 + r) * 18 + c] = f2h(eb[r] + beb_c);
            if constexpr (PASS == 1) {
                f32x4 gr = __builtin_amdgcn_mfma_f32_16x16x32_bf16(af, wg_f, zf, 0, 0, 0);
#pragma unroll
                for (int r = 0; r < 4; ++r) {
                    float gv = 1.f / (1.f + __expf(-(gr[r] + bg_c)));
                    aux[(g * 16 + quad * 4 + r) * 18 + c] = f2h(gv);
                }
            }
        }
        __syncthreads();
        // ---- stage 3: QK^T MFMA (hoisted loads) + softmax numerator ----
        short8 kf0 = z8, kf1 = z8;
        if (quad < 2) {
            kf0 = *(const short8*)(qkvT + (bN + m0 + c) * 768 + wv * 48 + 16 + quad * 8);
            kf1 = *(const short8*)(qkvT + (bN + m0 + 16 + c) * 768 + wv * 48 + 16 + quad * 8);
        }
        f32x4 sq0 = __builtin_amdgcn_mfma_f32_16x16x32_bf16(qf, kf0, zf, 0, 0, 0);
        f32x4 sq1 = __builtin_amdgcn_mfma_f32_16x16x32_bf16(qf, kf1, zf, 0, 0, 0);
#pragma unroll
        for (int k = 0; k < 2; ++k) {
#pragma unroll
            for (int r = 0; r < 4; ++r) {
                float sv = k ? sq1[r] : sq0[r];
                int row = (quad * 4 + r) * 32 + k * 16 + c;
                float s = fminf(fmaxf(sv, -5.f), 5.f) + h2f(eb_l[row * 18 + wv]);
                float pe = __expf(s - 8.f);
                if constexpr (PASS == 1) {
                    float gvv = h2f(aux[row * 18 + wv]);
                    den_r[r] += pe;
                    gs_r[r] += gvv;
                    tail[wv * 640 + (quad * 4 + r) * 40 + k * 16 + c] = f2bf(pe * gvv);
                } else {
                    aux[row * 24 + wv] = f2bf(pe * invd[r]);
                }
            }
        }
        // ---- stage 4 ----
        if constexpr (PASS == 1) {
            // same-wave tail: lgkmcnt is enough (no cross-wave LDS read here)
            asm volatile("s_waitcnt lgkmcnt(0)" ::: "memory");
            short8 pa = *(const short8*)(tail + wv * 640 + c * 40 + quad * 8);
            short8 vf = *(const short8*)(vT + (((size_t)(b * 16 + wv) * 16 + c) << 10) + m0 + quad * 8);
            acc_pv = __builtin_amdgcn_mfma_f32_16x16x32_bf16(pa, vf, acc_pv, 0, 0, 0);
        } else {
            __syncthreads();   // aux (p-hat) is read cross-wave below
            // ---- e-out + edge FFN, both row-groups batched ----
            // group g0=2*wv rows: (l = wv, m_loc = quad*4+r); g1: m_loc + 16
            // residual = anorm * sigma + mu; stats shuffled from stage-1 lanes
            // (lane 2j holds row wv*32+j). Read anorm BEFORE trs clobbers it.
            const int ar0 = wv * 32 + quad * 4;
            float res0[4], res1[4];
#pragma unroll
            for (int r = 0; r < 4; ++r) {
                int jr = quad * 4 + r;
                float mu0 = __shfl(muR, 2 * jr, 64);
                float sg0 = __shfl(sgR, 2 * jr, 64);
                float mu1 = __shfl(muR, 2 * jr + 32, 64);
                float sg1 = __shfl(sgR, 2 * jr + 32, 64);
                res0[r] = bf2f(anorm[(ar0 + r) * 24 + c]) * sg0 + mu0;
                res1[r] = bf2f(anorm[(ar0 + 16 + r) * 24 + c]) * sg1 + mu1;
            }
            short* t0 = (short*)tail + wv * 768;
            short* t1 = t0 + 384;
            const int g0 = wv * 2, g1 = g0 + 1;
            short8 pf0 = z8, pf1 = z8;
            if (quad < 2) {
                pf0 = *(const short8*)(aux + (g0 * 16 + c) * 24 + quad * 8);
                pf1 = *(const short8*)(aux + (g1 * 16 + c) * 24 + quad * 8);
            }
            f32x4 eo0 = __builtin_amdgcn_mfma_f32_16x16x32_bf16(pf0, weo_f, zf, 0, 0, 0);
            f32x4 eo1 = __builtin_amdgcn_mfma_f32_16x16x32_bf16(pf1, weo_f, zf, 0, 0, 0);
            const size_t gbase = ((bN + l0 + wv) * 1024 + m0 + quad * 4) * 16 + c;
            float ev0[4], ev1[4], hA[4], hB[4];
#pragma unroll
            for (int r = 0; r < 4; ++r) {
                ev0[r] = eo0[r] + beo_c + res0[r];
                ev1[r] = eo1[r] + beo_c + res1[r];
            }
#pragma unroll
            for (int r = 0; r < 4; ++r) {
                float a1 = ev0[r], a2 = ev0[r] * ev0[r];
                float b1v = ev1[r], b2 = ev1[r] * ev1[r];
#pragma unroll
                for (int mm = 1; mm < 16; mm <<= 1) {
                    a1 += __shfl_xor(a1, mm, 64); a2 += __shfl_xor(a2, mm, 64);
                    b1v += __shfl_xor(b1v, mm, 64); b2 += __shfl_xor(b2, mm, 64);
                }
                float muA = a1 * 0.0625f, rsA = rsqrtf(a2 * 0.0625f - muA * muA + 1e-5f);
                float muB = b1v * 0.0625f, rsB = rsqrtf(b2 * 0.0625f - muB * muB + 1e-5f);
                hA[r] = (ev0[r] - muA) * rsA;
                hB[r] = (ev1[r] - muB) * rsB;
            }
#pragma unroll
            for (int r = 0; r < 4; ++r) {
                t0[(quad * 4 + r) * 24 + c] = (short)f2bf(hA[r]);
                t1[(quad * 4 + r) * 24 + c] = (short)f2bf(hB[r]);
            }
            asm volatile("s_waitcnt lgkmcnt(0)" ::: "memory");
            short8 ea0 = z8, ea1 = z8;
            if (quad < 2) {
                ea0 = *(const short8*)(t0 + c * 24 + quad * 8);
                ea1 = *(const short8*)(t1 + c * 24 + quad * 8);
            }
            f32x4 tp0 = __builtin_amdgcn_mfma_f32_16x16x32_bf16(ea0, we1_f, zf, 0, 0, 0);
            f32x4 tp1 = __builtin_amdgcn_mfma_f32_16x16x32_bf16(ea1, we1_f, zf, 0, 0, 0);
#pragma unroll
            for (int r = 0; r < 4; ++r) {
                float x0v = tp0[r] + be1_c;
                float x1v = tp1[r] + be1_c;
                x0v = x0v > 0.f ? x0v : __expf(x0v) - 1.f;
                x1v = x1v > 0.f ? x1v : __expf(x1v) - 1.f;
                t0[(quad * 4 + r) * 24 + c] = (short)f2bf(x0v);
                t1[(quad * 4 + r) * 24 + c] = (short)f2bf(x1v);
            }
            asm volatile("s_waitcnt lgkmcnt(0)" ::: "memory");
            short8 ta0 = z8, ta1 = z8;
            if (quad < 2) {
                ta0 = *(const short8*)(t0 + c * 24 + quad * 8);
                ta1 = *(const short8*)(t1 + c * 24 + quad * 8);
            }
            f32x4 o20 = __builtin_amdgcn_mfma_f32_16x16x32_bf16(ta0, we2_f, zf, 0, 0, 0);
            f32x4 o21 = __builtin_amdgcn_mfma_f32_16x16x32_bf16(ta1, we2_f, zf, 0, 0, 0);
#pragma unroll
            for (int r = 0; r < 4; ++r) {
                ef_out[gbase + r * 16] = ev0[r] + o20[r] + be2_c;
                ef_out[gbase + 256 + r * 16] = ev1[r] + o21[r] + be2_c;
            }
        }
        // protect anorm/tail alias (and aux/eb_l lifetimes) across chunks
        __syncthreads();
    }

    if constexpr (PASS == 1) {
#pragma unroll
        for (int m = 1; m < 16; m <<= 1) {
#pragma unroll
            for (int r = 0; r < 4; ++r) {
                den_r[r] += __shfl_xor(den_r[r], m, 64);
                gs_r[r]  += __shfl_xor(gs_r[r], m, 64);
            }
        }
#pragma unroll
        for (int r = 0; r < 4; ++r) {
            int lg = l0 + quad * 4 + r;
            pacc[(size_t)half * 1048576 + (bN + lg) * 256 + c * 16 + wv] = acc_pv[r];
            if (c == 0) {
                pden[half * 65536 + (bN + lg) * 16 + wv] = den_r[r];
                pgs[half * 65536 + (bN + lg) * 16 + wv] = gs_r[r];
            }
        }
    }
}

extern "C" void kernel_launch(void* const* d_in, const int* in_sizes, int n_in,
                              void* d_out, int out_size, void* d_ws, size_t ws_size,
                              hipStream_t stream)
{
    const float* nfeat = (const float*)d_in[0];
    const float* efeat = (const float*)d_in[1];
    const float* ln_h_g = (const float*)d_in[2];
    const float* ln_h_b = (const float*)d_in[3];
    const float* ln_e_g = (const float*)d_in[4];
    const float* ln_e_b = (const float*)d_in[5];
    const float* w_eb = (const float*)d_in[6];
    const float* b_eb = (const float*)d_in[7];
    const float* w_g  = (const float*)d_in[8];
    const float* b_g  = (const float*)d_in[9];
    const float* w_qkv = (const float*)d_in[10];
    const float* b_qkv = (const float*)d_in[11];
    const float* w_no = (const float*)d_in[12];
    const float* b_no = (const float*)d_in[13];
    const float* ffn_ln_g = (const float*)d_in[14];
    const float* ffn_ln_b = (const float*)d_in[15];
    const float* w_f1 = (const float*)d_in[16];
    const float* b_f1 = (const float*)d_in[17];
    const float* w_f2 = (const float*)d_in[18];
    const float* b_f2 = (const float*)d_in[19];
    const float* w_eo = (const float*)d_in[20];
    const float* b_eo = (const float*)d_in[21];
    const float* effn_g = (const float*)d_in[22];
    const float* effn_b = (const float*)d_in[23];
    const float* w_e1 = (const float*)d_in[24];
    const float* b_e1 = (const float*)d_in[25];
    const float* w_e2 = (const float*)d_in[26];
    const float* b_e2 = (const float*)d_in[27];

    float* out_n = (float*)d_out;
    float* out_e = out_n + (size_t)1048576;

    char* ws = (char*)d_ws;
    // pacc [2][4096][256] f32 = 8 MiB, overlaps hln+qkvb (dead during P1)
    float* pacc          = (float*)(ws);
    unsigned short* hln  = (unsigned short*)(ws);                     // [0,2)
    unsigned short* qkvb = (unsigned short*)(ws + ((size_t)2 << 20)); // [2,8)
    unsigned short* qkvT = (unsigned short*)(ws + ((size_t)8 << 20)); // [8,14)
    unsigned short* vatt = (unsigned short*)(ws + ((size_t)14 << 20));// [14,16)
    // pden/pgs [2][4096][16] f32 = 512 KiB each, overlap hbuf (dead during P1)
    float* pden          = (float*)(ws + ((size_t)16 << 20));         // [16,16.5)
    float* pgs           = (float*)(ws + ((size_t)16 << 20) + 524288);// [16.5,17)
    float* hbuf          = (float*)(ws + ((size_t)16 << 20));         // [16,20)
    unsigned short* h2ln = (unsigned short*)(ws + ((size_t)20 << 20));// [20,22)
    unsigned short* tbuf = (unsigned short*)(ws + ((size_t)22 << 20));// [22,26)
    float* nf0           = (float*)(ws + ((size_t)26 << 20));         // [26,30)
    unsigned short* vT   = (unsigned short*)(ws + ((size_t)30 << 20));// [30,32)
    float* dbuf          = (float*)(ws + ((size_t)32 << 20));         // 256 KiB

    for (int l = 0; l < 2; ++l) {
        const float* nf_in = l ? nf0 : nfeat;
        const float* ef_in = l ? out_e : efeat;
        float* nf_out = l ? out_n : nf0;

        ln256_kernel<<<dim3(1024), dim3(256), 0, stream>>>(
            nf_in, ln_h_g + l * 256, ln_h_b + l * 256, hln);
        gemm_kernel<4><<<dim3(12, 64), dim3(256), 0, stream>>>(
            hln, w_qkv + l * 196608, b_qkv + l * 768,
            (const float*)nullptr, (float*)nullptr, qkvb, 4096, 256, 768);
        repack_kernel<<<dim3(4096), dim3(256), 0, stream>>>(qkvb, qkvT, vT);
        attn_kernel<1><<<dim3(512), dim3(1024), 0, stream>>>(
            ef_in, (float*)nullptr, qkvT, vT, pacc, pden, pgs, (const float*)nullptr,
            w_eb + l * 256, b_eb + l * 16, w_g + l * 256, b_g + l * 16,
            ln_e_g + l * 16, ln_e_b + l * 16,
            nullptr, nullptr, nullptr, nullptr, nullptr, nullptr, nullptr, nullptr);
        finalize_kernel<<<dim3(4096), dim3(256), 0, stream>>>(
            pacc, pden, pgs, vatt, dbuf);
        attn_kernel<2><<<dim3(512), dim3(1024), 0, stream>>>(
            ef_in, out_e, qkvT, (const unsigned short*)nullptr,
            (float*)nullptr, (float*)nullptr, (float*)nullptr, dbuf,
            w_eb + l * 256, b_eb + l * 16, nullptr, nullptr,
            ln_e_g + l * 16, ln_e_b + l * 16,
            w_eo + l * 256, b_eo + l * 16,
            effn_g + l * 16, effn_b + l * 16,
            w_e1 + l * 256, b_e1 + l * 16, w_e2 + l * 256, b_e2 + l * 16);
        gemm_kernel<2><<<dim3(4, 64), dim3(256), 0, stream>>>(
            vatt, w_no + l * 65536, b_no + l * 256, nf_in,
            hbuf, (unsigned short*)nullptr, 4096, 256, 256);
        ln256_kernel<<<dim3(1024), dim3(256), 0, stream>>>(
            hbuf, ffn_ln_g + l * 256, ffn_ln_b + l * 256, h2ln);
        gemm_kernel<5><<<dim3(8, 64), dim3(256), 0, stream>>>(
            h2ln, w_f1 + l * 131072, b_f1 + l * 512,
            (const float*)nullptr, (float*)nullptr, tbuf, 4096, 256, 512);
        gemm_kernel<2><<<dim3(4, 64), dim3(256), 0, stream>>>(
            tbuf, w_f2 + l * 131072, b_f2 + l * 256, hbuf,
            nf_out, (unsigned short*)nullptr, 4096, 512, 256);
    }
}

// Round 10
// 1013.941 us; speedup vs baseline: 1.0007x; 1.0007x over previous
//
#include <hip/hip_runtime.h>
#include <hip/hip_fp16.h>

#define B_ 4
#define N_ 1024

typedef __attribute__((ext_vector_type(8))) short short8;
typedef __attribute__((ext_vector_type(4))) float f32x4;
typedef __attribute__((ext_vector_type(4))) unsigned short us4;

static __device__ __forceinline__ unsigned short f2bf(float x) {
    union { float f; unsigned u; } v; v.f = x;
    unsigned r = v.u + 0x7FFFu + ((v.u >> 16) & 1u);
    return (unsigned short)(r >> 16);
}
static __device__ __forceinline__ float bf2f(unsigned short u) {
    union { unsigned x; float f; } v; v.x = (unsigned)u << 16; return v.f;
}
static __device__ __forceinline__ unsigned short f2h(float x) {
    __half h = __float2half(x); return __half_as_ushort(h);
}
static __device__ __forceinline__ float h2f(unsigned short u) {
    return __half2float(__ushort_as_half(u));
}

// ---------------- LayerNorm over 256 (one wave per row), bf16 out ----------
__global__ __launch_bounds__(256) void ln256_kernel(
    const float* __restrict__ x, const float* __restrict__ g,
    const float* __restrict__ bta, unsigned short* __restrict__ out)
{
    int row = blockIdx.x * 4 + (threadIdx.x >> 6);
    int lane = threadIdx.x & 63;
    const float4 v = *(const float4*)(x + (size_t)row * 256 + lane * 4);
    float s1 = v.x + v.y + v.z + v.w;
    float s2 = v.x * v.x + v.y * v.y + v.z * v.z + v.w * v.w;
#pragma unroll
    for (int m = 1; m < 64; m <<= 1) {
        s1 += __shfl_xor(s1, m, 64);
        s2 += __shfl_xor(s2, m, 64);
    }
    float mu = s1 * (1.f / 256.f);
    float var = s2 * (1.f / 256.f) - mu * mu;
    float rs = rsqrtf(var + 1e-5f);
    const float4 gv = *(const float4*)(g + lane * 4);
    const float4 bv = *(const float4*)(bta + lane * 4);
    us4 o;
    o[0] = f2bf((v.x - mu) * rs * gv.x + bv.x);
    o[1] = f2bf((v.y - mu) * rs * gv.y + bv.y);
    o[2] = f2bf((v.z - mu) * rs * gv.z + bv.z);
    o[3] = f2bf((v.w - mu) * rs * gv.w + bv.w);
    *(us4*)(out + (size_t)row * 256 + lane * 4) = o;
}

// ------ repack bf16 qkv [bn][(sd)*16+h] -> qkvT [bn][h][sd], vT [b][h][k][n]
__global__ __launch_bounds__(256) void repack_kernel(
    const unsigned short* __restrict__ qkvb, unsigned short* __restrict__ qkvT,
    unsigned short* __restrict__ vT)
{
    __shared__ unsigned short ld[768];
    int bn = blockIdx.x, t = threadIdx.x;
    const unsigned short* src = qkvb + (size_t)bn * 768;
    ld[t] = src[t]; ld[t + 256] = src[t + 256]; ld[t + 512] = src[t + 512];
    __syncthreads();
    unsigned short* dst = qkvT + (size_t)bn * 768;
#pragma unroll
    for (int i = 0; i < 3; ++i) {
        int o = t + i * 256;
        int h = o / 48, sd = o - h * 48;
        dst[o] = ld[sd * 16 + h];
    }
    int b = bn >> 10, n = bn & 1023;
    int h = t >> 4, k = t & 15;
    vT[(((size_t)(b * 16 + h) * 16 + k) << 10) + n] = ld[(32 + k) * 16 + h];
}

// ---------------- generic bf16 MFMA GEMM, 64x64 tile, BK=32 ----------------
// EPI bits: 1 = ELU, 2 = residual add, 4 = bf16 output
template <int EPI>
__global__ __launch_bounds__(256) void gemm_kernel(
    const unsigned short* __restrict__ A, const float* __restrict__ Bw,
    const float* __restrict__ bias, const float* __restrict__ res,
    float* __restrict__ outf, unsigned short* __restrict__ outh,
    int M, int K, int Nn)
{
    __shared__ __align__(16) short As[64][40];
    __shared__ __align__(16) short Bs[64][40];
    int tid = threadIdx.x;
    int n0 = blockIdx.x * 64, m0 = blockIdx.y * 64;
    int lane = tid & 63, wid = tid >> 6;
    int wm = (wid >> 1) * 32, wn = (wid & 1) * 32;
    int fr = lane & 15, quad = lane >> 4;
    f32x4 acc00 = {0.f,0.f,0.f,0.f}, acc01 = {0.f,0.f,0.f,0.f};
    f32x4 acc10 = {0.f,0.f,0.f,0.f}, acc11 = {0.f,0.f,0.f,0.f};
    int ar = tid >> 2, akc = (tid & 3) * 8;
    int bk = tid >> 3, bnc = (tid & 7) * 8;
    for (int k0 = 0; k0 < K; k0 += 32) {
        *(uint4*)&As[ar][akc] = *(const uint4*)(A + (size_t)(m0 + ar) * K + k0 + akc);
        const float* bp = Bw + (size_t)(k0 + bk) * Nn + n0 + bnc;
        float4 b1 = *(const float4*)bp;
        float4 b2 = *(const float4*)(bp + 4);
        Bs[bnc + 0][bk] = (short)f2bf(b1.x);
        Bs[bnc + 1][bk] = (short)f2bf(b1.y);
        Bs[bnc + 2][bk] = (short)f2bf(b1.z);
        Bs[bnc + 3][bk] = (short)f2bf(b1.w);
        Bs[bnc + 4][bk] = (short)f2bf(b2.x);
        Bs[bnc + 5][bk] = (short)f2bf(b2.y);
        Bs[bnc + 6][bk] = (short)f2bf(b2.z);
        Bs[bnc + 7][bk] = (short)f2bf(b2.w);
        __syncthreads();
        short8 af0 = *(const short8*)&As[wm + fr][quad * 8];
        short8 af1 = *(const short8*)&As[wm + 16 + fr][quad * 8];
        short8 bf0 = *(const short8*)&Bs[wn + fr][quad * 8];
        short8 bf1 = *(const short8*)&Bs[wn + 16 + fr][quad * 8];
        acc00 = __builtin_amdgcn_mfma_f32_16x16x32_bf16(af0, bf0, acc00, 0, 0, 0);
        acc01 = __builtin_amdgcn_mfma_f32_16x16x32_bf16(af0, bf1, acc01, 0, 0, 0);
        acc10 = __builtin_amdgcn_mfma_f32_16x16x32_bf16(af1, bf0, acc10, 0, 0, 0);
        acc11 = __builtin_amdgcn_mfma_f32_16x16x32_bf16(af1, bf1, acc11, 0, 0, 0);
        __syncthreads();
    }
#pragma unroll
    for (int fm = 0; fm < 2; ++fm) {
#pragma unroll
        for (int fn = 0; fn < 2; ++fn) {
            f32x4 a = (fm == 0) ? (fn == 0 ? acc00 : acc01) : (fn == 0 ? acc10 : acc11);
#pragma unroll
            for (int r = 0; r < 4; ++r) {
                int row = m0 + wm + fm * 16 + quad * 4 + r;
                int col = n0 + wn + fn * 16 + fr;
                float v = a[r] + bias[col];
                if (EPI & 2) v += res[(size_t)row * Nn + col];
                if (EPI & 1) v = v > 0.f ? v : __expf(v) - 1.f;
                if (EPI & 4) outh[(size_t)row * Nn + col] = f2bf(v);
                else         outf[(size_t)row * Nn + col] = v;
            }
        }
    }
}

// ------------------ fused edge attention (scores / recompute) --------------
// PASS 1: (b, 16-l tile), full m sweep: den/gs -> vattn,dbuf; optional pe->phat
// PASS 2 (fallback when ws too small): recompute s, e-out + edge FFN
template <int PASS>
__global__ __launch_bounds__(1024, 4) void attn_kernel(
    const float* __restrict__ ef_in, float* __restrict__ ef_out,
    const unsigned short* __restrict__ qkvT, const unsigned short* __restrict__ vT,
    unsigned short* __restrict__ vattn, float* __restrict__ dbuf,
    unsigned short* __restrict__ phat,
    const float* __restrict__ w_eb, const float* __restrict__ b_eb,
    const float* __restrict__ w_g,  const float* __restrict__ b_g,
    const float* __restrict__ ln_e_g, const float* __restrict__ ln_e_b,
    const float* __restrict__ w_eo, const float* __restrict__ b_eo,
    const float* __restrict__ effn_g, const float* __restrict__ effn_b,
    const float* __restrict__ w_e1, const float* __restrict__ b_e1,
    const float* __restrict__ w_e2, const float* __restrict__ b_e2)
{
    constexpr int ANORM_B = 512 * 24 * 2;
    constexpr int EB_B    = 512 * 18 * 2;
    constexpr int AUX_B   = (PASS == 1) ? 512 * 18 * 2 : 512 * 24 * 2;
    __shared__ __align__(16) char smem[ANORM_B + EB_B + AUX_B];
    unsigned short* anorm = (unsigned short*)smem;
    unsigned short* eb_l  = (unsigned short*)(smem + ANORM_B);
    unsigned short* aux   = (unsigned short*)(smem + ANORM_B + EB_B);
    unsigned short* tail  = anorm;

    const int bx = blockIdx.x;
    int b, lt, mbase, nchunk;
    if (PASS == 1) { b = bx >> 6; lt = bx & 63; mbase = 0; nchunk = 32; }
    else           { b = bx >> 7; lt = (bx >> 1) & 63; mbase = (bx & 1) * 512; nchunk = 16; }
    const int l0 = lt * 16;
    const int tid = threadIdx.x;
    const int wv = tid >> 6;
    const int lane = tid & 63;
    const int c = lane & 15;
    const int quad = lane >> 4;
    const size_t bN = (size_t)b * 1024;

    const short8 z8 = {0,0,0,0,0,0,0,0};
    const f32x4 zf = {0.f,0.f,0.f,0.f};

    float beb_c = b_eb[c], bg_c = 0.f, be1_c = 0.f, beo_c = 0.f, be2_c = 0.f;
    if constexpr (PASS == 1) bg_c = b_g[c];
    if constexpr (PASS == 2) { be1_c = b_e1[c]; beo_c = b_eo[c]; be2_c = b_e2[c]; }
    for (int e = 0; e < 16; ++e) {
        float lb = ln_e_b[e];
        beb_c += lb * w_eb[e * 16 + c];
        if constexpr (PASS == 1) bg_c += lb * w_g[e * 16 + c];
        if constexpr (PASS == 2) be1_c += effn_b[e] * w_e1[e * 16 + c];
    }
    short8 web_f = z8, wg_f = z8, weo_f = z8, we1_f = z8, we2_f = z8;
    if (quad < 2) {
#pragma unroll
        for (int j = 0; j < 8; ++j) {
            int e = quad * 8 + j;
            web_f[j] = (short)f2bf(ln_e_g[e] * w_eb[e * 16 + c]);
            if constexpr (PASS == 1) wg_f[j] = (short)f2bf(ln_e_g[e] * w_g[e * 16 + c]);
            if constexpr (PASS == 2) {
                weo_f[j] = (short)f2bf(w_eo[e * 16 + c]);
                we1_f[j] = (short)f2bf(effn_g[e] * w_e1[e * 16 + c]);
                we2_f[j] = (short)f2bf(w_e2[e * 16 + c]);
            }
        }
    }
    short8 qf = z8;
    if (quad < 2)
        qf = *(const short8*)(qkvT + (bN + l0 + c) * 768 + wv * 48 + quad * 8);

    float invd[4];
    float den_r[4] = {0.f,0.f,0.f,0.f}, gs_r[4] = {0.f,0.f,0.f,0.f};
    f32x4 acc_pv = zf;
    float muR = 0.f, sgR = 0.f;
    if constexpr (PASS == 2) {
#pragma unroll
        for (int r = 0; r < 4; ++r)
            invd[r] = dbuf[(bN + l0 + quad * 4 + r) * 16 + wv];
    }

    for (int ch = 0; ch < nchunk; ++ch) {
        const int m0 = mbase + ch * 32;
        // ---- stage 1: LN of efeat chunk -> anorm ----
        {
            int row = tid >> 1, halfw = tid & 1;
            int lr = row >> 5, mr = row & 31;
            const float* ep = ef_in + ((bN + l0 + lr) * 1024 + m0 + mr) * 16 + halfw * 8;
            float4 x0 = *(const float4*)ep;
            float4 x1 = *(const float4*)(ep + 4);
            float s1 = x0.x + x0.y + x0.z + x0.w + x1.x + x1.y + x1.z + x1.w;
            float s2 = x0.x*x0.x + x0.y*x0.y + x0.z*x0.z + x0.w*x0.w
                     + x1.x*x1.x + x1.y*x1.y + x1.z*x1.z + x1.w*x1.w;
            s1 += __shfl_xor(s1, 1, 64);
            s2 += __shfl_xor(s2, 1, 64);
            float mu = s1 * (1.f / 16.f);
            float vv = s2 * (1.f / 16.f) - mu * mu + 1e-5f;
            float rs = rsqrtf(vv);
            if constexpr (PASS == 2) { muR = mu; sgR = vv * rs; }
            short8 o;
            o[0] = (short)f2bf((x0.x - mu) * rs); o[1] = (short)f2bf((x0.y - mu) * rs);
            o[2] = (short)f2bf((x0.z - mu) * rs); o[3] = (short)f2bf((x0.w - mu) * rs);
            o[4] = (short)f2bf((x1.x - mu) * rs); o[5] = (short)f2bf((x1.y - mu) * rs);
            o[6] = (short)f2bf((x1.z - mu) * rs); o[7] = (short)f2bf((x1.w - mu) * rs);
            *(short8*)(anorm + row * 24 + halfw * 8) = o;
        }
        __syncthreads();
        // ---- stage 2: e_bias (+gates) MFMA ----
#pragma unroll
        for (int gg = 0; gg < 2; ++gg) {
            int g = wv * 2 + gg;
            short8 af = z8;
            if (quad < 2) af = *(const short8*)(anorm + (g * 16 + c) * 24 + quad * 8);
            f32x4 eb = __builtin_amdgcn_mfma_f32_16x16x32_bf16(af, web_f, zf, 0, 0, 0);
#pragma unroll
            for (int r = 0; r < 4; ++r)
                eb_l[(g * 16 + quad * 4 + r) * 18 + c] = f2h(eb[r] + beb_c);
            if constexpr (PASS == 1) {
                f32x4 gr = __builtin_amdgcn_mfma_f32_16x16x32_bf16(af, wg_f, zf, 0, 0, 0);
#pragma unroll
                for (int r = 0; r < 4; ++r) {
                    float gv = 1.f / (1.f + __expf(-(gr[r] + bg_c)));
                    aux[(g * 16 + quad * 4 + r) * 18 + c] = f2h(gv);
                }
            }
        }
        __syncthreads();
        // ---- stage 3: QK^T MFMA + softmax numerator ----
        short8 kf0 = z8, kf1 = z8;
        if (quad < 2) {
            kf0 = *(const short8*)(qkvT + (bN + m0 + c) * 768 + wv * 48 + 16 + quad * 8);
            kf1 = *(const short8*)(qkvT + (bN + m0 + 16 + c) * 768 + wv * 48 + 16 + quad * 8);
        }
        f32x4 sq0 = __builtin_amdgcn_mfma_f32_16x16x32_bf16(qf, kf0, zf, 0, 0, 0);
        f32x4 sq1 = __builtin_amdgcn_mfma_f32_16x16x32_bf16(qf, kf1, zf, 0, 0, 0);
#pragma unroll
        for (int k = 0; k < 2; ++k) {
#pragma unroll
            for (int r = 0; r < 4; ++r) {
                float sv = k ? sq1[r] : sq0[r];
                int row = (quad * 4 + r) * 32 + k * 16 + c;
                float s = fminf(fmaxf(sv, -5.f), 5.f) + h2f(eb_l[row * 18 + wv]);
                float pe = __expf(s - 8.f);
                if constexpr (PASS == 1) {
                    float gvv = h2f(aux[row * 18 + wv]);
                    den_r[r] += pe;
                    gs_r[r] += gvv;
                    tail[wv * 640 + (quad * 4 + r) * 40 + k * 16 + c] = f2bf(pe * gvv);
                    if (phat)
                        phat[((bN + l0 + quad * 4 + r) * 1024 + (size_t)(m0 + k * 16 + c)) * 16 + wv]
                            = f2bf(pe);
                } else {
                    aux[row * 24 + wv] = f2bf(pe * invd[r]);
                }
            }
        }
        // ---- stage 4 ----
        if constexpr (PASS == 1) {
            asm volatile("s_waitcnt lgkmcnt(0)" ::: "memory");
            short8 pa = *(const short8*)(tail + wv * 640 + c * 40 + quad * 8);
            short8 vf = *(const short8*)(vT + (((size_t)(b * 16 + wv) * 16 + c) << 10) + m0 + quad * 8);
            acc_pv = __builtin_amdgcn_mfma_f32_16x16x32_bf16(pa, vf, acc_pv, 0, 0, 0);
        } else {
            __syncthreads();
            const int ar0 = wv * 32 + quad * 4;
            float res0[4], res1[4];
#pragma unroll
            for (int r = 0; r < 4; ++r) {
                int jr = quad * 4 + r;
                float mu0 = __shfl(muR, 2 * jr, 64);
                float sg0 = __shfl(sgR, 2 * jr, 64);
                float mu1 = __shfl(muR, 2 * jr + 32, 64);
                float sg1 = __shfl(sgR, 2 * jr + 32, 64);
                res0[r] = bf2f(anorm[(ar0 + r) * 24 + c]) * sg0 + mu0;
                res1[r] = bf2f(anorm[(ar0 + 16 + r) * 24 + c]) * sg1 + mu1;
            }
            short* t0 = (short*)tail + wv * 768;
            short* t1 = t0 + 384;
            const int g0 = wv * 2, g1 = g0 + 1;
            short8 pf0 = z8, pf1 = z8;
            if (quad < 2) {
                pf0 = *(const short8*)(aux + (g0 * 16 + c) * 24 + quad * 8);
                pf1 = *(const short8*)(aux + (g1 * 16 + c) * 24 + quad * 8);
            }
            f32x4 eo0 = __builtin_amdgcn_mfma_f32_16x16x32_bf16(pf0, weo_f, zf, 0, 0, 0);
            f32x4 eo1 = __builtin_amdgcn_mfma_f32_16x16x32_bf16(pf1, weo_f, zf, 0, 0, 0);
            const size_t gbase = ((bN + l0 + wv) * 1024 + m0 + quad * 4) * 16 + c;
            float ev0[4], ev1[4], hA[4], hB[4];
#pragma unroll
            for (int r = 0; r < 4; ++r) {
                ev0[r] = eo0[r] + beo_c + res0[r];
                ev1[r] = eo1[r] + beo_c + res1[r];
            }
#pragma unroll
            for (int r = 0; r < 4; ++r) {
                float a1 = ev0[r], a2 = ev0[r] * ev0[r];
                float b1v = ev1[r], b2 = ev1[r] * ev1[r];
#pragma unroll
                for (int mm = 1; mm < 16; mm <<= 1) {
                    a1 += __shfl_xor(a1, mm, 64); a2 += __shfl_xor(a2, mm, 64);
                    b1v += __shfl_xor(b1v, mm, 64); b2 += __shfl_xor(b2, mm, 64);
                }
                float muA = a1 * 0.0625f, rsA = rsqrtf(a2 * 0.0625f - muA * muA + 1e-5f);
                float muB = b1v * 0.0625f, rsB = rsqrtf(b2 * 0.0625f - muB * muB + 1e-5f);
                hA[r] = (ev0[r] - muA) * rsA;
                hB[r] = (ev1[r] - muB) * rsB;
            }
#pragma unroll
            for (int r = 0; r < 4; ++r) {
                t0[(quad * 4 + r) * 24 + c] = (short)f2bf(hA[r]);
                t1[(quad * 4 + r) * 24 + c] = (short)f2bf(hB[r]);
            }
            asm volatile("s_waitcnt lgkmcnt(0)" ::: "memory");
            short8 ea0 = z8, ea1 = z8;
            if (quad < 2) {
                ea0 = *(const short8*)(t0 + c * 24 + quad * 8);
                ea1 = *(const short8*)(t1 + c * 24 + quad * 8);
            }
            f32x4 tp0 = __builtin_amdgcn_mfma_f32_16x16x32_bf16(ea0, we1_f, zf, 0, 0, 0);
            f32x4 tp1 = __builtin_amdgcn_mfma_f32_16x16x32_bf16(ea1, we1_f, zf, 0, 0, 0);
#pragma unroll
            for (int r = 0; r < 4; ++r) {
                float x0v = tp0[r] + be1_c;
                float x1v = tp1[r] + be1_c;
                x0v = x0v > 0.f ? x0v : __expf(x0v) - 1.f;
                x1v = x1v > 0.f ? x1v : __expf(x1v) - 1.f;
                t0[(quad * 4 + r) * 24 + c] = (short)f2bf(x0v);
                t1[(quad * 4 + r) * 24 + c] = (short)f2bf(x1v);
            }
            asm volatile("s_waitcnt lgkmcnt(0)" ::: "memory");
            short8 ta0 = z8, ta1 = z8;
            if (quad < 2) {
                ta0 = *(const short8*)(t0 + c * 24 + quad * 8);
                ta1 = *(const short8*)(t1 + c * 24 + quad * 8);
            }
            f32x4 o20 = __builtin_amdgcn_mfma_f32_16x16x32_bf16(ta0, we2_f, zf, 0, 0, 0);
            f32x4 o21 = __builtin_amdgcn_mfma_f32_16x16x32_bf16(ta1, we2_f, zf, 0, 0, 0);
#pragma unroll
            for (int r = 0; r < 4; ++r) {
                ef_out[gbase + r * 16] = ev0[r] + o20[r] + be2_c;
                ef_out[gbase + 256 + r * 16] = ev1[r] + o21[r] + be2_c;
            }
        }
        __syncthreads();
    }

    if constexpr (PASS == 1) {
#pragma unroll
        for (int m = 1; m < 16; m <<= 1) {
#pragma unroll
            for (int r = 0; r < 4; ++r) {
                den_r[r] += __shfl_xor(den_r[r], m, 64);
                gs_r[r]  += __shfl_xor(gs_r[r], m, 64);
            }
        }
#pragma unroll
        for (int r = 0; r < 4; ++r) {
            float id = 1.f / den_r[r];
            int lg = l0 + quad * 4 + r;
            float sc = (lg == 0) ? 1.f : log1pf(gs_r[r]);
            vattn[(bN + lg) * 256 + c * 16 + wv] = f2bf(acc_pv[r] * id * sc);
            if (c == 0) dbuf[(bN + lg) * 16 + wv] = id;
        }
    }
}

// ---- e-out + edge FFN from materialized pe: barrier-free, 1 wave = 1 row --
__global__ __launch_bounds__(512) void eout_kernel(
    const float* __restrict__ ef_in, float* __restrict__ ef_out,
    const unsigned short* __restrict__ phat, const float* __restrict__ dbuf,
    const float* __restrict__ w_eo, const float* __restrict__ b_eo,
    const float* __restrict__ effn_g, const float* __restrict__ effn_b,
    const float* __restrict__ w_e1, const float* __restrict__ b_e1,
    const float* __restrict__ w_e2, const float* __restrict__ b_e2)
{
    __shared__ __align__(16) short trs[8 * 768];
    const int bx = blockIdx.x;                 // (b<<8)|(lo<<1)|half
    const int b = bx >> 8;
    const int lo = (bx >> 1) & 127;
    const int half = bx & 1;
    const int tid = threadIdx.x;
    const int wv = tid >> 6;                   // 0..7
    const int lane = tid & 63;
    const int c = lane & 15;
    const int quad = lane >> 4;
    const size_t rowl = (size_t)b * 1024 + lo * 8 + wv;

    const short8 z8 = {0,0,0,0,0,0,0,0};
    const f32x4 zf = {0.f,0.f,0.f,0.f};

    float beo_c = b_eo[c], be1_c = b_e1[c], be2_c = b_e2[c];
    for (int e = 0; e < 16; ++e) be1_c += effn_b[e] * w_e1[e * 16 + c];
    short8 weo_f = z8, we1_f = z8, we2_f = z8;
    if (quad < 2) {
#pragma unroll
        for (int j = 0; j < 8; ++j) {
            int e = quad * 8 + j;
            weo_f[j] = (short)f2bf(dbuf[rowl * 16 + e] * w_eo[e * 16 + c]);
            we1_f[j] = (short)f2bf(effn_g[e] * w_e1[e * 16 + c]);
            we2_f[j] = (short)f2bf(w_e2[e * 16 + c]);
        }
    }
    short* t0 = (short*)trs + wv * 768;
    short* t1 = t0 + 384;

    for (int ch = 0; ch < 16; ++ch) {
        const int m0 = half * 512 + ch * 32;
        short8 pa0 = z8, pa1 = z8;
        if (quad < 2) {
            pa0 = *(const short8*)(phat + (rowl * 1024 + m0 + c) * 16 + quad * 8);
            pa1 = *(const short8*)(phat + (rowl * 1024 + m0 + 16 + c) * 16 + quad * 8);
        }
        f32x4 eo0 = __builtin_amdgcn_mfma_f32_16x16x32_bf16(pa0, weo_f, zf, 0, 0, 0);
        f32x4 eo1 = __builtin_amdgcn_mfma_f32_16x16x32_bf16(pa1, weo_f, zf, 0, 0, 0);
        const size_t gbase = (rowl * 1024 + m0 + quad * 4) * 16 + c;
        float ev0[4], ev1[4], hA[4], hB[4];
#pragma unroll
        for (int r = 0; r < 4; ++r) {
            ev0[r] = eo0[r] + beo_c + ef_in[gbase + r * 16];
            ev1[r] = eo1[r] + beo_c + ef_in[gbase + 256 + r * 16];
        }
#pragma unroll
        for (int r = 0; r < 4; ++r) {
            float a1 = ev0[r], a2 = ev0[r] * ev0[r];
            float b1v = ev1[r], b2 = ev1[r] * ev1[r];
#pragma unroll
            for (int mm = 1; mm < 16; mm <<= 1) {
                a1 += __shfl_xor(a1, mm, 64); a2 += __shfl_xor(a2, mm, 64);
                b1v += __shfl_xor(b1v, mm, 64); b2 += __shfl_xor(b2, mm, 64);
            }
            float muA = a1 * 0.0625f, rsA = rsqrtf(a2 * 0.0625f - muA * muA + 1e-5f);
            float muB = b1v * 0.0625f, rsB = rsqrtf(b2 * 0.0625f - muB * muB + 1e-5f);
            hA[r] = (ev0[r] - muA) * rsA;
            hB[r] = (ev1[r] - muB) * rsB;
        }
#pragma unroll
        for (int r = 0; r < 4; ++r) {
            t0[(quad * 4 + r) * 24 + c] = (short)f2bf(hA[r]);
            t1[(quad * 4 + r) * 24 + c] = (short)f2bf(hB[r]);
        }
        asm volatile("s_waitcnt lgkmcnt(0)" ::: "memory");
        short8 ea0 = z8, ea1 = z8;
        if (quad < 2) {
            ea0 = *(const short8*)(t0 + c * 24 + quad * 8);
            ea1 = *(const short8*)(t1 + c * 24 + quad * 8);
        }
        f32x4 tp0 = __builtin_amdgcn_mfma_f32_16x16x32_bf16(ea0, we1_f, zf, 0, 0, 0);
        f32x4 tp1 = __builtin_amdgcn_mfma_f32_16x16x32_bf16(ea1, we1_f, zf, 0, 0, 0);
#pragma unroll
        for (int r = 0; r < 4; ++r) {
            float x0v = tp0[r] + be1_c;
            float x1v = tp1[r] + be1_c;
            x0v = x0v > 0.f ? x0v : __expf(x0v) - 1.f;
            x1v = x1v > 0.f ? x1v : __expf(x1v) - 1.f;
            t0[(quad * 4 + r) * 24 + c] = (short)f2bf(x0v);
            t1[(quad * 4 + r) * 24 + c] = (short)f2bf(x1v);
        }
        asm volatile("s_waitcnt lgkmcnt(0)" ::: "memory");
        short8 ta0 = z8, ta1 = z8;
        if (quad < 2) {
            ta0 = *(const short8*)(t0 + c * 24 + quad * 8);
            ta1 = *(const short8*)(t1 + c * 24 + quad * 8);
        }
        f32x4 o20 = __builtin_amdgcn_mfma_f32_16x16x32_bf16(ta0, we2_f, zf, 0, 0, 0);
        f32x4 o21 = __builtin_amdgcn_mfma_f32_16x16x32_bf16(ta1, we2_f, zf, 0, 0, 0);
#pragma unroll
        for (int r = 0; r < 4; ++r) {
            ef_out[gbase + r * 16] = ev0[r] + o20[r] + be2_c;
            ef_out[gbase + 256 + r * 16] = ev1[r] + o21[r] + be2_c;
        }
    }
}

extern "C" void kernel_launch(void* const* d_in, const int* in_sizes, int n_in,
                              void* d_out, int out_size, void* d_ws, size_t ws_size,
                              hipStream_t stream)
{
    const float* nfeat = (const float*)d_in[0];
    const float* efeat = (const float*)d_in[1];
    const float* ln_h_g = (const float*)d_in[2];
    const float* ln_h_b = (const float*)d_in[3];
    const float* ln_e_g = (const float*)d_in[4];
    const float* ln_e_b = (const float*)d_in[5];
    const float* w_eb = (const float*)d_in[6];
    const float* b_eb = (const float*)d_in[7];
    const float* w_g  = (const float*)d_in[8];
    const float* b_g  = (const float*)d_in[9];
    const float* w_qkv = (const float*)d_in[10];
    const float* b_qkv = (const float*)d_in[11];
    const float* w_no = (const float*)d_in[12];
    const float* b_no = (const float*)d_in[13];
    const float* ffn_ln_g = (const float*)d_in[14];
    const float* ffn_ln_b = (const float*)d_in[15];
    const float* w_f1 = (const float*)d_in[16];
    const float* b_f1 = (const float*)d_in[17];
    const float* w_f2 = (const float*)d_in[18];
    const float* b_f2 = (const float*)d_in[19];
    const float* w_eo = (const float*)d_in[20];
    const float* b_eo = (const float*)d_in[21];
    const float* effn_g = (const float*)d_in[22];
    const float* effn_b = (const float*)d_in[23];
    const float* w_e1 = (const float*)d_in[24];
    const float* b_e1 = (const float*)d_in[25];
    const float* w_e2 = (const float*)d_in[26];
    const float* b_e2 = (const float*)d_in[27];

    float* out_n = (float*)d_out;
    float* out_e = out_n + (size_t)1048576;

    char* ws = (char*)d_ws;
    unsigned short* hln  = (unsigned short*)(ws);                     // [0,2)
    unsigned short* qkvb = (unsigned short*)(ws + ((size_t)2 << 20)); // [2,8)
    unsigned short* qkvT = (unsigned short*)(ws + ((size_t)8 << 20)); // [8,14)
    unsigned short* vatt = (unsigned short*)(ws + ((size_t)14 << 20));// [14,16)
    float* hbuf          = (float*)(ws + ((size_t)16 << 20));         // [16,20)
    unsigned short* h2ln = (unsigned short*)(ws + ((size_t)20 << 20));// [20,22)
    unsigned short* tbuf = (unsigned short*)(ws + ((size_t)22 << 20));// [22,26)
    float* nf0           = (float*)(ws + ((size_t)26 << 20));         // [26,30)
    unsigned short* vT   = (unsigned short*)(ws + ((size_t)30 << 20));// [30,32)
    float* dbuf          = (float*)(ws + ((size_t)32 << 20));         // 256 KiB
    const bool use_phat  = ws_size >= ((size_t)169 << 20);
    unsigned short* phat = use_phat ? (unsigned short*)(ws + ((size_t)34 << 20)) : nullptr;

    for (int l = 0; l < 2; ++l) {
        const float* nf_in = l ? nf0 : nfeat;
        const float* ef_in = l ? out_e : efeat;
        float* nf_out = l ? out_n : nf0;

        ln256_kernel<<<dim3(1024), dim3(256), 0, stream>>>(
            nf_in, ln_h_g + l * 256, ln_h_b + l * 256, hln);
        gemm_kernel<4><<<dim3(12, 64), dim3(256), 0, stream>>>(
            hln, w_qkv + l * 196608, b_qkv + l * 768,
            (const float*)nullptr, (float*)nullptr, qkvb, 4096, 256, 768);
        repack_kernel<<<dim3(4096), dim3(256), 0, stream>>>(qkvb, qkvT, vT);
        attn_kernel<1><<<dim3(256), dim3(1024), 0, stream>>>(
            ef_in, (float*)nullptr, qkvT, vT, vatt, dbuf, phat,
            w_eb + l * 256, b_eb + l * 16, w_g + l * 256, b_g + l * 16,
            ln_e_g + l * 16, ln_e_b + l * 16,
            nullptr, nullptr, nullptr, nullptr, nullptr, nullptr, nullptr, nullptr);
        if (use_phat) {
            eout_kernel<<<dim3(1024), dim3(512), 0, stream>>>(
                ef_in, out_e, phat, dbuf,
                w_eo + l * 256, b_eo + l * 16,
                effn_g + l * 16, effn_b + l * 16,
                w_e1 + l * 256, b_e1 + l * 16, w_e2 + l * 256, b_e2 + l * 16);
        } else {
            attn_kernel<2><<<dim3(512), dim3(1024), 0, stream>>>(
                ef_in, out_e, qkvT, (const unsigned short*)nullptr,
                (unsigned short*)nullptr, dbuf, (unsigned short*)nullptr,
                w_eb + l * 256, b_eb + l * 16, nullptr, nullptr,
                ln_e_g + l * 16, ln_e_b + l * 16,
                w_eo + l * 256, b_eo + l * 16,
                effn_g + l * 16, effn_b + l * 16,
                w_e1 + l * 256, b_e1 + l * 16, w_e2 + l * 256, b_e2 + l * 16);
        }
        gemm_kernel<2><<<dim3(4, 64), dim3(256), 0, stream>>>(
            vatt, w_no + l * 65536, b_no + l * 256, nf_in,
            hbuf, (unsigned short*)nullptr, 4096, 256, 256);
        ln256_kernel<<<dim3(1024), dim3(256), 0, stream>>>(
            hbuf, ffn_ln_g + l * 256, ffn_ln_b + l * 256, h2ln);
        gemm_kernel<5><<<dim3(8, 64), dim3(256), 0, stream>>>(
            h2ln, w_f1 + l * 131072, b_f1 + l * 512,
            (const float*)nullptr, (float*)nullptr, tbuf, 4096, 256, 512);
        gemm_kernel<2><<<dim3(4, 64), dim3(256), 0, stream>>>(
            tbuf, w_f2 + l * 131072, b_f2 + l * 256, hbuf,
            nf_out, (unsigned short*)nullptr, 4096, 512, 256);
    }
}

// Round 11
// 803.304 us; speedup vs baseline: 1.2632x; 1.2622x over previous
//
#include <hip/hip_runtime.h>
#include <hip/hip_fp16.h>

#define B_ 4
#define N_ 1024

typedef __attribute__((ext_vector_type(8))) short short8;
typedef __attribute__((ext_vector_type(4))) float f32x4;
typedef __attribute__((ext_vector_type(4))) unsigned short us4;

static __device__ __forceinline__ unsigned short f2bf(float x) {
    union { float f; unsigned u; } v; v.f = x;
    unsigned r = v.u + 0x7FFFu + ((v.u >> 16) & 1u);
    return (unsigned short)(r >> 16);
}
static __device__ __forceinline__ float bf2f(unsigned short u) {
    union { unsigned x; float f; } v; v.x = (unsigned)u << 16; return v.f;
}
static __device__ __forceinline__ unsigned short f2h(float x) {
    __half h = __float2half(x); return __half_as_ushort(h);
}
static __device__ __forceinline__ float h2f(unsigned short u) {
    return __half2float(__ushort_as_half(u));
}

// ---------------- LayerNorm over 256 (one wave per row), bf16 out ----------
__global__ __launch_bounds__(256) void ln256_kernel(
    const float* __restrict__ x, const float* __restrict__ g,
    const float* __restrict__ bta, unsigned short* __restrict__ out)
{
    int row = blockIdx.x * 4 + (threadIdx.x >> 6);
    int lane = threadIdx.x & 63;
    const float4 v = *(const float4*)(x + (size_t)row * 256 + lane * 4);
    float s1 = v.x + v.y + v.z + v.w;
    float s2 = v.x * v.x + v.y * v.y + v.z * v.z + v.w * v.w;
#pragma unroll
    for (int m = 1; m < 64; m <<= 1) {
        s1 += __shfl_xor(s1, m, 64);
        s2 += __shfl_xor(s2, m, 64);
    }
    float mu = s1 * (1.f / 256.f);
    float var = s2 * (1.f / 256.f) - mu * mu;
    float rs = rsqrtf(var + 1e-5f);
    const float4 gv = *(const float4*)(g + lane * 4);
    const float4 bv = *(const float4*)(bta + lane * 4);
    us4 o;
    o[0] = f2bf((v.x - mu) * rs * gv.x + bv.x);
    o[1] = f2bf((v.y - mu) * rs * gv.y + bv.y);
    o[2] = f2bf((v.z - mu) * rs * gv.z + bv.z);
    o[3] = f2bf((v.w - mu) * rs * gv.w + bv.w);
    *(us4*)(out + (size_t)row * 256 + lane * 4) = o;
}

// ------ repack bf16 qkv [bn][(sd)*16+h] -> qkvT [bn][h][sd], vT [b][h][k][n]
__global__ __launch_bounds__(256) void repack_kernel(
    const unsigned short* __restrict__ qkvb, unsigned short* __restrict__ qkvT,
    unsigned short* __restrict__ vT)
{
    __shared__ unsigned short ld[768];
    int bn = blockIdx.x, t = threadIdx.x;
    const unsigned short* src = qkvb + (size_t)bn * 768;
    ld[t] = src[t]; ld[t + 256] = src[t + 256]; ld[t + 512] = src[t + 512];
    __syncthreads();
    unsigned short* dst = qkvT + (size_t)bn * 768;
#pragma unroll
    for (int i = 0; i < 3; ++i) {
        int o = t + i * 256;
        int h = o / 48, sd = o - h * 48;
        dst[o] = ld[sd * 16 + h];
    }
    int b = bn >> 10, n = bn & 1023;
    int h = t >> 4, k = t & 15;
    vT[(((size_t)(b * 16 + h) * 16 + k) << 10) + n] = ld[(32 + k) * 16 + h];
}

// ---------------- generic bf16 MFMA GEMM, 64x64 tile, BK=32 ----------------
// EPI bits: 1 = ELU, 2 = residual add, 4 = bf16 output
template <int EPI>
__global__ __launch_bounds__(256) void gemm_kernel(
    const unsigned short* __restrict__ A, const float* __restrict__ Bw,
    const float* __restrict__ bias, const float* __restrict__ res,
    float* __restrict__ outf, unsigned short* __restrict__ outh,
    int M, int K, int Nn)
{
    __shared__ __align__(16) short As[64][40];
    __shared__ __align__(16) short Bs[64][40];
    int tid = threadIdx.x;
    int n0 = blockIdx.x * 64, m0 = blockIdx.y * 64;
    int lane = tid & 63, wid = tid >> 6;
    int wm = (wid >> 1) * 32, wn = (wid & 1) * 32;
    int fr = lane & 15, quad = lane >> 4;
    f32x4 acc00 = {0.f,0.f,0.f,0.f}, acc01 = {0.f,0.f,0.f,0.f};
    f32x4 acc10 = {0.f,0.f,0.f,0.f}, acc11 = {0.f,0.f,0.f,0.f};
    int ar = tid >> 2, akc = (tid & 3) * 8;
    int bk = tid >> 3, bnc = (tid & 7) * 8;
    for (int k0 = 0; k0 < K; k0 += 32) {
        *(uint4*)&As[ar][akc] = *(const uint4*)(A + (size_t)(m0 + ar) * K + k0 + akc);
        const float* bp = Bw + (size_t)(k0 + bk) * Nn + n0 + bnc;
        float4 b1 = *(const float4*)bp;
        float4 b2 = *(const float4*)(bp + 4);
        Bs[bnc + 0][bk] = (short)f2bf(b1.x);
        Bs[bnc + 1][bk] = (short)f2bf(b1.y);
        Bs[bnc + 2][bk] = (short)f2bf(b1.z);
        Bs[bnc + 3][bk] = (short)f2bf(b1.w);
        Bs[bnc + 4][bk] = (short)f2bf(b2.x);
        Bs[bnc + 5][bk] = (short)f2bf(b2.y);
        Bs[bnc + 6][bk] = (short)f2bf(b2.z);
        Bs[bnc + 7][bk] = (short)f2bf(b2.w);
        __syncthreads();
        short8 af0 = *(const short8*)&As[wm + fr][quad * 8];
        short8 af1 = *(const short8*)&As[wm + 16 + fr][quad * 8];
        short8 bf0 = *(const short8*)&Bs[wn + fr][quad * 8];
        short8 bf1 = *(const short8*)&Bs[wn + 16 + fr][quad * 8];
        acc00 = __builtin_amdgcn_mfma_f32_16x16x32_bf16(af0, bf0, acc00, 0, 0, 0);
        acc01 = __builtin_amdgcn_mfma_f32_16x16x32_bf16(af0, bf1, acc01, 0, 0, 0);
        acc10 = __builtin_amdgcn_mfma_f32_16x16x32_bf16(af1, bf0, acc10, 0, 0, 0);
        acc11 = __builtin_amdgcn_mfma_f32_16x16x32_bf16(af1, bf1, acc11, 0, 0, 0);
        __syncthreads();
    }
#pragma unroll
    for (int fm = 0; fm < 2; ++fm) {
#pragma unroll
        for (int fn = 0; fn < 2; ++fn) {
            f32x4 a = (fm == 0) ? (fn == 0 ? acc00 : acc01) : (fn == 0 ? acc10 : acc11);
#pragma unroll
            for (int r = 0; r < 4; ++r) {
                int row = m0 + wm + fm * 16 + quad * 4 + r;
                int col = n0 + wn + fn * 16 + fr;
                float v = a[r] + bias[col];
                if (EPI & 2) v += res[(size_t)row * Nn + col];
                if (EPI & 1) v = v > 0.f ? v : __expf(v) - 1.f;
                if (EPI & 4) outh[(size_t)row * Nn + col] = f2bf(v);
                else         outf[(size_t)row * Nn + col] = v;
            }
        }
    }
}

// ------------------ fused edge attention (scores / recompute) --------------
// PASS 1: (b, 16-l tile), full m sweep: den/gs -> vattn,dbuf; optional pe->phat
//         phat layout [b][l][h][m]: lanes (fixed h=wv, contiguous c->m) write
//         32B segments; k=0/1 fill adjacent halves of 64B lines (WC-friendly).
// PASS 2 (fallback when ws too small): recompute s, e-out + edge FFN
template <int PASS>
__global__ __launch_bounds__(1024, 4) void attn_kernel(
    const float* __restrict__ ef_in, float* __restrict__ ef_out,
    const unsigned short* __restrict__ qkvT, const unsigned short* __restrict__ vT,
    unsigned short* __restrict__ vattn, float* __restrict__ dbuf,
    unsigned short* __restrict__ phat,
    const float* __restrict__ w_eb, const float* __restrict__ b_eb,
    const float* __restrict__ w_g,  const float* __restrict__ b_g,
    const float* __restrict__ ln_e_g, const float* __restrict__ ln_e_b,
    const float* __restrict__ w_eo, const float* __restrict__ b_eo,
    const float* __restrict__ effn_g, const float* __restrict__ effn_b,
    const float* __restrict__ w_e1, const float* __restrict__ b_e1,
    const float* __restrict__ w_e2, const float* __restrict__ b_e2)
{
    constexpr int ANORM_B = 512 * 24 * 2;
    constexpr int EB_B    = 512 * 18 * 2;
    constexpr int AUX_B   = (PASS == 1) ? 512 * 18 * 2 : 512 * 24 * 2;
    __shared__ __align__(16) char smem[ANORM_B + EB_B + AUX_B];
    unsigned short* anorm = (unsigned short*)smem;
    unsigned short* eb_l  = (unsigned short*)(smem + ANORM_B);
    unsigned short* aux   = (unsigned short*)(smem + ANORM_B + EB_B);
    unsigned short* tail  = anorm;

    const int bx = blockIdx.x;
    int b, lt, mbase, nchunk;
    if (PASS == 1) { b = bx >> 6; lt = bx & 63; mbase = 0; nchunk = 32; }
    else           { b = bx >> 7; lt = (bx >> 1) & 63; mbase = (bx & 1) * 512; nchunk = 16; }
    const int l0 = lt * 16;
    const int tid = threadIdx.x;
    const int wv = tid >> 6;
    const int lane = tid & 63;
    const int c = lane & 15;
    const int quad = lane >> 4;
    const size_t bN = (size_t)b * 1024;

    const short8 z8 = {0,0,0,0,0,0,0,0};
    const f32x4 zf = {0.f,0.f,0.f,0.f};

    float beb_c = b_eb[c], bg_c = 0.f, be1_c = 0.f, beo_c = 0.f, be2_c = 0.f;
    if constexpr (PASS == 1) bg_c = b_g[c];
    if constexpr (PASS == 2) { be1_c = b_e1[c]; beo_c = b_eo[c]; be2_c = b_e2[c]; }
    for (int e = 0; e < 16; ++e) {
        float lb = ln_e_b[e];
        beb_c += lb * w_eb[e * 16 + c];
        if constexpr (PASS == 1) bg_c += lb * w_g[e * 16 + c];
        if constexpr (PASS == 2) be1_c += effn_b[e] * w_e1[e * 16 + c];
    }
    short8 web_f = z8, wg_f = z8, weo_f = z8, we1_f = z8, we2_f = z8;
    if (quad < 2) {
#pragma unroll
        for (int j = 0; j < 8; ++j) {
            int e = quad * 8 + j;
            web_f[j] = (short)f2bf(ln_e_g[e] * w_eb[e * 16 + c]);
            if constexpr (PASS == 1) wg_f[j] = (short)f2bf(ln_e_g[e] * w_g[e * 16 + c]);
            if constexpr (PASS == 2) {
                weo_f[j] = (short)f2bf(w_eo[e * 16 + c]);
                we1_f[j] = (short)f2bf(effn_g[e] * w_e1[e * 16 + c]);
                we2_f[j] = (short)f2bf(w_e2[e * 16 + c]);
            }
        }
    }
    short8 qf = z8;
    if (quad < 2)
        qf = *(const short8*)(qkvT + (bN + l0 + c) * 768 + wv * 48 + quad * 8);

    float invd[4];
    float den_r[4] = {0.f,0.f,0.f,0.f}, gs_r[4] = {0.f,0.f,0.f,0.f};
    f32x4 acc_pv = zf;
    float muR = 0.f, sgR = 0.f;
    if constexpr (PASS == 2) {
#pragma unroll
        for (int r = 0; r < 4; ++r)
            invd[r] = dbuf[(bN + l0 + quad * 4 + r) * 16 + wv];
    }

    for (int ch = 0; ch < nchunk; ++ch) {
        const int m0 = mbase + ch * 32;
        // ---- stage 1: LN of efeat chunk -> anorm ----
        {
            int row = tid >> 1, halfw = tid & 1;
            int lr = row >> 5, mr = row & 31;
            const float* ep = ef_in + ((bN + l0 + lr) * 1024 + m0 + mr) * 16 + halfw * 8;
            float4 x0 = *(const float4*)ep;
            float4 x1 = *(const float4*)(ep + 4);
            float s1 = x0.x + x0.y + x0.z + x0.w + x1.x + x1.y + x1.z + x1.w;
            float s2 = x0.x*x0.x + x0.y*x0.y + x0.z*x0.z + x0.w*x0.w
                     + x1.x*x1.x + x1.y*x1.y + x1.z*x1.z + x1.w*x1.w;
            s1 += __shfl_xor(s1, 1, 64);
            s2 += __shfl_xor(s2, 1, 64);
            float mu = s1 * (1.f / 16.f);
            float vv = s2 * (1.f / 16.f) - mu * mu + 1e-5f;
            float rs = rsqrtf(vv);
            if constexpr (PASS == 2) { muR = mu; sgR = vv * rs; }
            short8 o;
            o[0] = (short)f2bf((x0.x - mu) * rs); o[1] = (short)f2bf((x0.y - mu) * rs);
            o[2] = (short)f2bf((x0.z - mu) * rs); o[3] = (short)f2bf((x0.w - mu) * rs);
            o[4] = (short)f2bf((x1.x - mu) * rs); o[5] = (short)f2bf((x1.y - mu) * rs);
            o[6] = (short)f2bf((x1.z - mu) * rs); o[7] = (short)f2bf((x1.w - mu) * rs);
            *(short8*)(anorm + row * 24 + halfw * 8) = o;
        }
        __syncthreads();
        // ---- stage 2: e_bias (+gates) MFMA ----
#pragma unroll
        for (int gg = 0; gg < 2; ++gg) {
            int g = wv * 2 + gg;
            short8 af = z8;
            if (quad < 2) af = *(const short8*)(anorm + (g * 16 + c) * 24 + quad * 8);
            f32x4 eb = __builtin_amdgcn_mfma_f32_16x16x32_bf16(af, web_f, zf, 0, 0, 0);
#pragma unroll
            for (int r = 0; r < 4; ++r)
                eb_l[(g * 16 + quad * 4 + r) * 18 + c] = f2h(eb[r] + beb_c);
            if constexpr (PASS == 1) {
                f32x4 gr = __builtin_amdgcn_mfma_f32_16x16x32_bf16(af, wg_f, zf, 0, 0, 0);
#pragma unroll
                for (int r = 0; r < 4; ++r) {
                    float gv = 1.f / (1.f + __expf(-(gr[r] + bg_c)));
                    aux[(g * 16 + quad * 4 + r) * 18 + c] = f2h(gv);
                }
            }
        }
        __syncthreads();
        // ---- stage 3: QK^T MFMA + softmax numerator ----
        short8 kf0 = z8, kf1 = z8;
        if (quad < 2) {
            kf0 = *(const short8*)(qkvT + (bN + m0 + c) * 768 + wv * 48 + 16 + quad * 8);
            kf1 = *(const short8*)(qkvT + (bN + m0 + 16 + c) * 768 + wv * 48 + 16 + quad * 8);
        }
        f32x4 sq0 = __builtin_amdgcn_mfma_f32_16x16x32_bf16(qf, kf0, zf, 0, 0, 0);
        f32x4 sq1 = __builtin_amdgcn_mfma_f32_16x16x32_bf16(qf, kf1, zf, 0, 0, 0);
#pragma unroll
        for (int k = 0; k < 2; ++k) {
#pragma unroll
            for (int r = 0; r < 4; ++r) {
                float sv = k ? sq1[r] : sq0[r];
                int row = (quad * 4 + r) * 32 + k * 16 + c;
                float s = fminf(fmaxf(sv, -5.f), 5.f) + h2f(eb_l[row * 18 + wv]);
                float pe = __expf(s - 8.f);
                if constexpr (PASS == 1) {
                    float gvv = h2f(aux[row * 18 + wv]);
                    den_r[r] += pe;
                    gs_r[r] += gvv;
                    tail[wv * 640 + (quad * 4 + r) * 40 + k * 16 + c] = f2bf(pe * gvv);
                    if (phat)
                        phat[((bN + l0 + quad * 4 + r) * 16 + wv) * 1024
                             + (size_t)(m0 + k * 16 + c)] = f2bf(pe);
                } else {
                    aux[row * 24 + wv] = f2bf(pe * invd[r]);
                }
            }
        }
        // ---- stage 4 ----
        if constexpr (PASS == 1) {
            asm volatile("s_waitcnt lgkmcnt(0)" ::: "memory");
            short8 pa = *(const short8*)(tail + wv * 640 + c * 40 + quad * 8);
            short8 vf = *(const short8*)(vT + (((size_t)(b * 16 + wv) * 16 + c) << 10) + m0 + quad * 8);
            acc_pv = __builtin_amdgcn_mfma_f32_16x16x32_bf16(pa, vf, acc_pv, 0, 0, 0);
        } else {
            __syncthreads();
            const int ar0 = wv * 32 + quad * 4;
            float res0[4], res1[4];
#pragma unroll
            for (int r = 0; r < 4; ++r) {
                int jr = quad * 4 + r;
                float mu0 = __shfl(muR, 2 * jr, 64);
                float sg0 = __shfl(sgR, 2 * jr, 64);
                float mu1 = __shfl(muR, 2 * jr + 32, 64);
                float sg1 = __shfl(sgR, 2 * jr + 32, 64);
                res0[r] = bf2f(anorm[(ar0 + r) * 24 + c]) * sg0 + mu0;
                res1[r] = bf2f(anorm[(ar0 + 16 + r) * 24 + c]) * sg1 + mu1;
            }
            short* t0 = (short*)tail + wv * 768;
            short* t1 = t0 + 384;
            const int g0 = wv * 2, g1 = g0 + 1;
            short8 pf0 = z8, pf1 = z8;
            if (quad < 2) {
                pf0 = *(const short8*)(aux + (g0 * 16 + c) * 24 + quad * 8);
                pf1 = *(const short8*)(aux + (g1 * 16 + c) * 24 + quad * 8);
            }
            f32x4 eo0 = __builtin_amdgcn_mfma_f32_16x16x32_bf16(pf0, weo_f, zf, 0, 0, 0);
            f32x4 eo1 = __builtin_amdgcn_mfma_f32_16x16x32_bf16(pf1, weo_f, zf, 0, 0, 0);
            const size_t gbase = ((bN + l0 + wv) * 1024 + m0 + quad * 4) * 16 + c;
            float ev0[4], ev1[4], hA[4], hB[4];
#pragma unroll
            for (int r = 0; r < 4; ++r) {
                ev0[r] = eo0[r] + beo_c + res0[r];
                ev1[r] = eo1[r] + beo_c + res1[r];
            }
#pragma unroll
            for (int r = 0; r < 4; ++r) {
                float a1 = ev0[r], a2 = ev0[r] * ev0[r];
                float b1v = ev1[r], b2 = ev1[r] * ev1[r];
#pragma unroll
                for (int mm = 1; mm < 16; mm <<= 1) {
                    a1 += __shfl_xor(a1, mm, 64); a2 += __shfl_xor(a2, mm, 64);
                    b1v += __shfl_xor(b1v, mm, 64); b2 += __shfl_xor(b2, mm, 64);
                }
                float muA = a1 * 0.0625f, rsA = rsqrtf(a2 * 0.0625f - muA * muA + 1e-5f);
                float muB = b1v * 0.0625f, rsB = rsqrtf(b2 * 0.0625f - muB * muB + 1e-5f);
                hA[r] = (ev0[r] - muA) * rsA;
                hB[r] = (ev1[r] - muB) * rsB;
            }
#pragma unroll
            for (int r = 0; r < 4; ++r) {
                t0[(quad * 4 + r) * 24 + c] = (short)f2bf(hA[r]);
                t1[(quad * 4 + r) * 24 + c] = (short)f2bf(hB[r]);
            }
            asm volatile("s_waitcnt lgkmcnt(0)" ::: "memory");
            short8 ea0 = z8, ea1 = z8;
            if (quad < 2) {
                ea0 = *(const short8*)(t0 + c * 24 + quad * 8);
                ea1 = *(const short8*)(t1 + c * 24 + quad * 8);
            }
            f32x4 tp0 = __builtin_amdgcn_mfma_f32_16x16x32_bf16(ea0, we1_f, zf, 0, 0, 0);
            f32x4 tp1 = __builtin_amdgcn_mfma_f32_16x16x32_bf16(ea1, we1_f, zf, 0, 0, 0);
#pragma unroll
            for (int r = 0; r < 4; ++r) {
                float x0v = tp0[r] + be1_c;
                float x1v = tp1[r] + be1_c;
                x0v = x0v > 0.f ? x0v : __expf(x0v) - 1.f;
                x1v = x1v > 0.f ? x1v : __expf(x1v) - 1.f;
                t0[(quad * 4 + r) * 24 + c] = (short)f2bf(x0v);
                t1[(quad * 4 + r) * 24 + c] = (short)f2bf(x1v);
            }
            asm volatile("s_waitcnt lgkmcnt(0)" ::: "memory");
            short8 ta0 = z8, ta1 = z8;
            if (quad < 2) {
                ta0 = *(const short8*)(t0 + c * 24 + quad * 8);
                ta1 = *(const short8*)(t1 + c * 24 + quad * 8);
            }
            f32x4 o20 = __builtin_amdgcn_mfma_f32_16x16x32_bf16(ta0, we2_f, zf, 0, 0, 0);
            f32x4 o21 = __builtin_amdgcn_mfma_f32_16x16x32_bf16(ta1, we2_f, zf, 0, 0, 0);
#pragma unroll
            for (int r = 0; r < 4; ++r) {
                ef_out[gbase + r * 16] = ev0[r] + o20[r] + be2_c;
                ef_out[gbase + 256 + r * 16] = ev1[r] + o21[r] + be2_c;
            }
        }
        __syncthreads();
    }

    if constexpr (PASS == 1) {
#pragma unroll
        for (int m = 1; m < 16; m <<= 1) {
#pragma unroll
            for (int r = 0; r < 4; ++r) {
                den_r[r] += __shfl_xor(den_r[r], m, 64);
                gs_r[r]  += __shfl_xor(gs_r[r], m, 64);
            }
        }
#pragma unroll
        for (int r = 0; r < 4; ++r) {
            float id = 1.f / den_r[r];
            int lg = l0 + quad * 4 + r;
            float sc = (lg == 0) ? 1.f : log1pf(gs_r[r]);
            vattn[(bN + lg) * 256 + c * 16 + wv] = f2bf(acc_pv[r] * id * sc);
            if (c == 0) dbuf[(bN + lg) * 16 + wv] = id;
        }
    }
}

// ---- e-out + edge FFN from materialized pe: barrier-free, 1 wave = 1 row --
// phat is [b][l][h][m]; per chunk each lane does one coalesced 16B load and
// the wave transposes to pes[m][h] (stride 24, b128-aligned) in its own LDS.
__global__ __launch_bounds__(512) void eout_kernel(
    const float* __restrict__ ef_in, float* __restrict__ ef_out,
    const unsigned short* __restrict__ phat, const float* __restrict__ dbuf,
    const float* __restrict__ w_eo, const float* __restrict__ b_eo,
    const float* __restrict__ effn_g, const float* __restrict__ effn_b,
    const float* __restrict__ w_e1, const float* __restrict__ b_e1,
    const float* __restrict__ w_e2, const float* __restrict__ b_e2)
{
    __shared__ __align__(16) short trs[8 * 768];
    __shared__ __align__(16) short pes[8 * 768];   // per wave: [32 m][24] (h in 0..15)
    const int bx = blockIdx.x;                 // (b<<8)|(lo<<1)|half
    const int b = bx >> 8;
    const int lo = (bx >> 1) & 127;
    const int half = bx & 1;
    const int tid = threadIdx.x;
    const int wv = tid >> 6;                   // 0..7
    const int lane = tid & 63;
    const int c = lane & 15;
    const int quad = lane >> 4;
    const size_t rowl = (size_t)b * 1024 + lo * 8 + wv;

    const short8 z8 = {0,0,0,0,0,0,0,0};
    const f32x4 zf = {0.f,0.f,0.f,0.f};

    float beo_c = b_eo[c], be1_c = b_e1[c], be2_c = b_e2[c];
    for (int e = 0; e < 16; ++e) be1_c += effn_b[e] * w_e1[e * 16 + c];
    short8 weo_f = z8, we1_f = z8, we2_f = z8;
    if (quad < 2) {
#pragma unroll
        for (int j = 0; j < 8; ++j) {
            int e = quad * 8 + j;
            weo_f[j] = (short)f2bf(dbuf[rowl * 16 + e] * w_eo[e * 16 + c]);
            we1_f[j] = (short)f2bf(effn_g[e] * w_e1[e * 16 + c]);
            we2_f[j] = (short)f2bf(w_e2[e * 16 + c]);
        }
    }
    short* t0 = (short*)trs + wv * 768;
    short* t1 = t0 + 384;
    short* pesw = (short*)pes + wv * 768;
    const int hh2 = lane >> 2, mseg = lane & 3;

    for (int ch = 0; ch < 16; ++ch) {
        const int m0 = half * 512 + ch * 32;
        // stage pe chunk: coalesced load (lane = h*?; 16B of pe[h][m..m+8])
        {
            uint4 pv = *(const uint4*)(phat + ((rowl * 16 + hh2) << 10) + m0 + mseg * 8);
            const unsigned short* pw = (const unsigned short*)&pv;
#pragma unroll
            for (int j = 0; j < 8; ++j)
                pesw[(mseg * 8 + j) * 24 + hh2] = (short)pw[j];
        }
        asm volatile("s_waitcnt lgkmcnt(0)" ::: "memory");
        short8 pa0 = z8, pa1 = z8;
        if (quad < 2) {
            pa0 = *(const short8*)(pesw + c * 24 + quad * 8);
            pa1 = *(const short8*)(pesw + (c + 16) * 24 + quad * 8);
        }
        f32x4 eo0 = __builtin_amdgcn_mfma_f32_16x16x32_bf16(pa0, weo_f, zf, 0, 0, 0);
        f32x4 eo1 = __builtin_amdgcn_mfma_f32_16x16x32_bf16(pa1, weo_f, zf, 0, 0, 0);
        const size_t gbase = (rowl * 1024 + m0 + quad * 4) * 16 + c;
        float ev0[4], ev1[4], hA[4], hB[4];
#pragma unroll
        for (int r = 0; r < 4; ++r) {
            ev0[r] = eo0[r] + beo_c + ef_in[gbase + r * 16];
            ev1[r] = eo1[r] + beo_c + ef_in[gbase + 256 + r * 16];
        }
#pragma unroll
        for (int r = 0; r < 4; ++r) {
            float a1 = ev0[r], a2 = ev0[r] * ev0[r];
            float b1v = ev1[r], b2 = ev1[r] * ev1[r];
#pragma unroll
            for (int mm = 1; mm < 16; mm <<= 1) {
                a1 += __shfl_xor(a1, mm, 64); a2 += __shfl_xor(a2, mm, 64);
                b1v += __shfl_xor(b1v, mm, 64); b2 += __shfl_xor(b2, mm, 64);
            }
            float muA = a1 * 0.0625f, rsA = rsqrtf(a2 * 0.0625f - muA * muA + 1e-5f);
            float muB = b1v * 0.0625f, rsB = rsqrtf(b2 * 0.0625f - muB * muB + 1e-5f);
            hA[r] = (ev0[r] - muA) * rsA;
            hB[r] = (ev1[r] - muB) * rsB;
        }
#pragma unroll
        for (int r = 0; r < 4; ++r) {
            t0[(quad * 4 + r) * 24 + c] = (short)f2bf(hA[r]);
            t1[(quad * 4 + r) * 24 + c] = (short)f2bf(hB[r]);
        }
        asm volatile("s_waitcnt lgkmcnt(0)" ::: "memory");
        short8 ea0 = z8, ea1 = z8;
        if (quad < 2) {
            ea0 = *(const short8*)(t0 + c * 24 + quad * 8);
            ea1 = *(const short8*)(t1 + c * 24 + quad * 8);
        }
        f32x4 tp0 = __builtin_amdgcn_mfma_f32_16x16x32_bf16(ea0, we1_f, zf, 0, 0, 0);
        f32x4 tp1 = __builtin_amdgcn_mfma_f32_16x16x32_bf16(ea1, we1_f, zf, 0, 0, 0);
#pragma unroll
        for (int r = 0; r < 4; ++r) {
            float x0v = tp0[r] + be1_c;
            float x1v = tp1[r] + be1_c;
            x0v = x0v > 0.f ? x0v : __expf(x0v) - 1.f;
            x1v = x1v > 0.f ? x1v : __expf(x1v) - 1.f;
            t0[(quad * 4 + r) * 24 + c] = (short)f2bf(x0v);
            t1[(quad * 4 + r) * 24 + c] = (short)f2bf(x1v);
        }
        asm volatile("s_waitcnt lgkmcnt(0)" ::: "memory");
        short8 ta0 = z8, ta1 = z8;
        if (quad < 2) {
            ta0 = *(const short8*)(t0 + c * 24 + quad * 8);
            ta1 = *(const short8*)(t1 + c * 24 + quad * 8);
        }
        f32x4 o20 = __builtin_amdgcn_mfma_f32_16x16x32_bf16(ta0, we2_f, zf, 0, 0, 0);
        f32x4 o21 = __builtin_amdgcn_mfma_f32_16x16x32_bf16(ta1, we2_f, zf, 0, 0, 0);
#pragma unroll
        for (int r = 0; r < 4; ++r) {
            ef_out[gbase + r * 16] = ev0[r] + o20[r] + be2_c;
            ef_out[gbase + 256 + r * 16] = ev1[r] + o21[r] + be2_c;
        }
    }
}

extern "C" void kernel_launch(void* const* d_in, const int* in_sizes, int n_in,
                              void* d_out, int out_size, void* d_ws, size_t ws_size,
                              hipStream_t stream)
{
    const float* nfeat = (const float*)d_in[0];
    const float* efeat = (const float*)d_in[1];
    const float* ln_h_g = (const float*)d_in[2];
    const float* ln_h_b = (const float*)d_in[3];
    const float* ln_e_g = (const float*)d_in[4];
    const float* ln_e_b = (const float*)d_in[5];
    const float* w_eb = (const float*)d_in[6];
    const float* b_eb = (const float*)d_in[7];
    const float* w_g  = (const float*)d_in[8];
    const float* b_g  = (const float*)d_in[9];
    const float* w_qkv = (const float*)d_in[10];
    const float* b_qkv = (const float*)d_in[11];
    const float* w_no = (const float*)d_in[12];
    const float* b_no = (const float*)d_in[13];
    const float* ffn_ln_g = (const float*)d_in[14];
    const float* ffn_ln_b = (const float*)d_in[15];
    const float* w_f1 = (const float*)d_in[16];
    const float* b_f1 = (const float*)d_in[17];
    const float* w_f2 = (const float*)d_in[18];
    const float* b_f2 = (const float*)d_in[19];
    const float* w_eo = (const float*)d_in[20];
    const float* b_eo = (const float*)d_in[21];
    const float* effn_g = (const float*)d_in[22];
    const float* effn_b = (const float*)d_in[23];
    const float* w_e1 = (const float*)d_in[24];
    const float* b_e1 = (const float*)d_in[25];
    const float* w_e2 = (const float*)d_in[26];
    const float* b_e2 = (const float*)d_in[27];

    float* out_n = (float*)d_out;
    float* out_e = out_n + (size_t)1048576;

    char* ws = (char*)d_ws;
    unsigned short* hln  = (unsigned short*)(ws);                     // [0,2)
    unsigned short* qkvb = (unsigned short*)(ws + ((size_t)2 << 20)); // [2,8)
    unsigned short* qkvT = (unsigned short*)(ws + ((size_t)8 << 20)); // [8,14)
    unsigned short* vatt = (unsigned short*)(ws + ((size_t)14 << 20));// [14,16)
    float* hbuf          = (float*)(ws + ((size_t)16 << 20));         // [16,20)
    unsigned short* h2ln = (unsigned short*)(ws + ((size_t)20 << 20));// [20,22)
    unsigned short* tbuf = (unsigned short*)(ws + ((size_t)22 << 20));// [22,26)
    float* nf0           = (float*)(ws + ((size_t)26 << 20));         // [26,30)
    unsigned short* vT   = (unsigned short*)(ws + ((size_t)30 << 20));// [30,32)
    float* dbuf          = (float*)(ws + ((size_t)32 << 20));         // 256 KiB
    const bool use_phat  = ws_size >= ((size_t)169 << 20);
    unsigned short* phat = use_phat ? (unsigned short*)(ws + ((size_t)34 << 20)) : nullptr;

    for (int l = 0; l < 2; ++l) {
        const float* nf_in = l ? nf0 : nfeat;
        const float* ef_in = l ? out_e : efeat;
        float* nf_out = l ? out_n : nf0;

        ln256_kernel<<<dim3(1024), dim3(256), 0, stream>>>(
            nf_in, ln_h_g + l * 256, ln_h_b + l * 256, hln);
        gemm_kernel<4><<<dim3(12, 64), dim3(256), 0, stream>>>(
            hln, w_qkv + l * 196608, b_qkv + l * 768,
            (const float*)nullptr, (float*)nullptr, qkvb, 4096, 256, 768);
        repack_kernel<<<dim3(4096), dim3(256), 0, stream>>>(qkvb, qkvT, vT);
        attn_kernel<1><<<dim3(256), dim3(1024), 0, stream>>>(
            ef_in, (float*)nullptr, qkvT, vT, vatt, dbuf, phat,
            w_eb + l * 256, b_eb + l * 16, w_g + l * 256, b_g + l * 16,
            ln_e_g + l * 16, ln_e_b + l * 16,
            nullptr, nullptr, nullptr, nullptr, nullptr, nullptr, nullptr, nullptr);
        if (use_phat) {
            eout_kernel<<<dim3(1024), dim3(512), 0, stream>>>(
                ef_in, out_e, phat, dbuf,
                w_eo + l * 256, b_eo + l * 16,
                effn_g + l * 16, effn_b + l * 16,
                w_e1 + l * 256, b_e1 + l * 16, w_e2 + l * 256, b_e2 + l * 16);
        } else {
            attn_kernel<2><<<dim3(512), dim3(1024), 0, stream>>>(
                ef_in, out_e, qkvT, (const unsigned short*)nullptr,
                (unsigned short*)nullptr, dbuf, (unsigned short*)nullptr,
                w_eb + l * 256, b_eb + l * 16, nullptr, nullptr,
                ln_e_g + l * 16, ln_e_b + l * 16,
                w_eo + l * 256, b_eo + l * 16,
                effn_g + l * 16, effn_b + l * 16,
                w_e1 + l * 256, b_e1 + l * 16, w_e2 + l * 256, b_e2 + l * 16);
        }
        gemm_kernel<2><<<dim3(4, 64), dim3(256), 0, stream>>>(
            vatt, w_no + l * 65536, b_no + l * 256, nf_in,
            hbuf, (unsigned short*)nullptr, 4096, 256, 256);
        ln256_kernel<<<dim3(1024), dim3(256), 0, stream>>>(
            hbuf, ffn_ln_g + l * 256, ffn_ln_b + l * 256, h2ln);
        gemm_kernel<5><<<dim3(8, 64), dim3(256), 0, stream>>>(
            h2ln, w_f1 + l * 131072, b_f1 + l * 512,
            (const float*)nullptr, (float*)nullptr, tbuf, 4096, 256, 512);
        gemm_kernel<2><<<dim3(4, 64), dim3(256), 0, stream>>>(
            tbuf, w_f2 + l * 131072, b_f2 + l * 256, hbuf,
            nf_out, (unsigned short*)nullptr, 4096, 512, 256);
    }
}

// Round 12
// 789.489 us; speedup vs baseline: 1.2853x; 1.0175x over previous
//
#include <hip/hip_runtime.h>
#include <hip/hip_fp16.h>
#include <hip/hip_bf16.h>

#define B_ 4
#define N_ 1024
#define L2E 1.44269504f

typedef __attribute__((ext_vector_type(8))) short short8;
typedef __attribute__((ext_vector_type(4))) float f32x4;
typedef __attribute__((ext_vector_type(4))) unsigned short us4;

static __device__ __forceinline__ unsigned short f2bf(float x) {
    __hip_bfloat16 b = __float2bfloat16(x);
    union { __hip_bfloat16 b; unsigned short u; } v; v.b = b; return v.u;
}
static __device__ __forceinline__ float bf2f(unsigned short u) {
    union { unsigned x; float f; } v; v.x = (unsigned)u << 16; return v.f;
}
static __device__ __forceinline__ unsigned short f2h(float x) {
    __half h = __float2half(x); return __half_as_ushort(h);
}
static __device__ __forceinline__ float h2f(unsigned short u) {
    return __half2float(__ushort_as_half(u));
}

// ---------------- LayerNorm over 256 (one wave per row), bf16 out ----------
__global__ __launch_bounds__(256) void ln256_kernel(
    const float* __restrict__ x, const float* __restrict__ g,
    const float* __restrict__ bta, unsigned short* __restrict__ out)
{
    int row = blockIdx.x * 4 + (threadIdx.x >> 6);
    int lane = threadIdx.x & 63;
    const float4 v = *(const float4*)(x + (size_t)row * 256 + lane * 4);
    float s1 = v.x + v.y + v.z + v.w;
    float s2 = v.x * v.x + v.y * v.y + v.z * v.z + v.w * v.w;
#pragma unroll
    for (int m = 1; m < 64; m <<= 1) {
        s1 += __shfl_xor(s1, m, 64);
        s2 += __shfl_xor(s2, m, 64);
    }
    float mu = s1 * (1.f / 256.f);
    float var = s2 * (1.f / 256.f) - mu * mu;
    float rs = rsqrtf(var + 1e-5f);
    const float4 gv = *(const float4*)(g + lane * 4);
    const float4 bv = *(const float4*)(bta + lane * 4);
    us4 o;
    o[0] = f2bf((v.x - mu) * rs * gv.x + bv.x);
    o[1] = f2bf((v.y - mu) * rs * gv.y + bv.y);
    o[2] = f2bf((v.z - mu) * rs * gv.z + bv.z);
    o[3] = f2bf((v.w - mu) * rs * gv.w + bv.w);
    *(us4*)(out + (size_t)row * 256 + lane * 4) = o;
}

// ------ repack bf16 qkv [bn][(sd)*16+h] -> qkvT [bn][h][sd], vT [b][h][k][n]
__global__ __launch_bounds__(256) void repack_kernel(
    const unsigned short* __restrict__ qkvb, unsigned short* __restrict__ qkvT,
    unsigned short* __restrict__ vT)
{
    __shared__ unsigned short ld[768];
    int bn = blockIdx.x, t = threadIdx.x;
    const unsigned short* src = qkvb + (size_t)bn * 768;
    ld[t] = src[t]; ld[t + 256] = src[t + 256]; ld[t + 512] = src[t + 512];
    __syncthreads();
    unsigned short* dst = qkvT + (size_t)bn * 768;
#pragma unroll
    for (int i = 0; i < 3; ++i) {
        int o = t + i * 256;
        int h = o / 48, sd = o - h * 48;
        dst[o] = ld[sd * 16 + h];
    }
    int b = bn >> 10, n = bn & 1023;
    int h = t >> 4, k = t & 15;
    vT[(((size_t)(b * 16 + h) * 16 + k) << 10) + n] = ld[(32 + k) * 16 + h];
}

// ---------------- generic bf16 MFMA GEMM, 64x64 tile, BK=32 ----------------
// EPI bits: 1 = ELU, 2 = residual add, 4 = bf16 output
template <int EPI>
__global__ __launch_bounds__(256) void gemm_kernel(
    const unsigned short* __restrict__ A, const float* __restrict__ Bw,
    const float* __restrict__ bias, const float* __restrict__ res,
    float* __restrict__ outf, unsigned short* __restrict__ outh,
    int M, int K, int Nn)
{
    __shared__ __align__(16) short As[64][40];
    __shared__ __align__(16) short Bs[64][40];
    int tid = threadIdx.x;
    int n0 = blockIdx.x * 64, m0 = blockIdx.y * 64;
    int lane = tid & 63, wid = tid >> 6;
    int wm = (wid >> 1) * 32, wn = (wid & 1) * 32;
    int fr = lane & 15, quad = lane >> 4;
    f32x4 acc00 = {0.f,0.f,0.f,0.f}, acc01 = {0.f,0.f,0.f,0.f};
    f32x4 acc10 = {0.f,0.f,0.f,0.f}, acc11 = {0.f,0.f,0.f,0.f};
    int ar = tid >> 2, akc = (tid & 3) * 8;
    int bk = tid >> 3, bnc = (tid & 7) * 8;
    for (int k0 = 0; k0 < K; k0 += 32) {
        *(uint4*)&As[ar][akc] = *(const uint4*)(A + (size_t)(m0 + ar) * K + k0 + akc);
        const float* bp = Bw + (size_t)(k0 + bk) * Nn + n0 + bnc;
        float4 b1 = *(const float4*)bp;
        float4 b2 = *(const float4*)(bp + 4);
        Bs[bnc + 0][bk] = (short)f2bf(b1.x);
        Bs[bnc + 1][bk] = (short)f2bf(b1.y);
        Bs[bnc + 2][bk] = (short)f2bf(b1.z);
        Bs[bnc + 3][bk] = (short)f2bf(b1.w);
        Bs[bnc + 4][bk] = (short)f2bf(b2.x);
        Bs[bnc + 5][bk] = (short)f2bf(b2.y);
        Bs[bnc + 6][bk] = (short)f2bf(b2.z);
        Bs[bnc + 7][bk] = (short)f2bf(b2.w);
        __syncthreads();
        short8 af0 = *(const short8*)&As[wm + fr][quad * 8];
        short8 af1 = *(const short8*)&As[wm + 16 + fr][quad * 8];
        short8 bf0 = *(const short8*)&Bs[wn + fr][quad * 8];
        short8 bf1 = *(const short8*)&Bs[wn + 16 + fr][quad * 8];
        acc00 = __builtin_amdgcn_mfma_f32_16x16x32_bf16(af0, bf0, acc00, 0, 0, 0);
        acc01 = __builtin_amdgcn_mfma_f32_16x16x32_bf16(af0, bf1, acc01, 0, 0, 0);
        acc10 = __builtin_amdgcn_mfma_f32_16x16x32_bf16(af1, bf0, acc10, 0, 0, 0);
        acc11 = __builtin_amdgcn_mfma_f32_16x16x32_bf16(af1, bf1, acc11, 0, 0, 0);
        __syncthreads();
    }
#pragma unroll
    for (int fm = 0; fm < 2; ++fm) {
#pragma unroll
        for (int fn = 0; fn < 2; ++fn) {
            f32x4 a = (fm == 0) ? (fn == 0 ? acc00 : acc01) : (fn == 0 ? acc10 : acc11);
#pragma unroll
            for (int r = 0; r < 4; ++r) {
                int row = m0 + wm + fm * 16 + quad * 4 + r;
                int col = n0 + wn + fn * 16 + fr;
                float v = a[r] + bias[col];
                if (EPI & 2) v += res[(size_t)row * Nn + col];
                if (EPI & 1) v = v > 0.f ? v : __expf(v) - 1.f;
                if (EPI & 4) outh[(size_t)row * Nn + col] = f2bf(v);
                else         outf[(size_t)row * Nn + col] = v;
            }
        }
    }
}

// ------------------ fused edge attention (scores / recompute) --------------
// PASS 1: (b, 16-l tile), full m sweep: den/gs -> vattn,dbuf; pe -> phat
//         [b][l][h][m] (writer-coalesced). 2 barriers/chunk: S1->S2 is
//         wave-local (lgkmcnt fence only; R6 evidence), S2->S3 + chunk-end.
// PASS 2 (fallback when ws too small): recompute s, e-out + edge FFN
template <int PASS>
__global__ __launch_bounds__(1024, 4) void attn_kernel(
    const float* __restrict__ ef_in, float* __restrict__ ef_out,
    const unsigned short* __restrict__ qkvT, const unsigned short* __restrict__ vT,
    unsigned short* __restrict__ vattn, float* __restrict__ dbuf,
    unsigned short* __restrict__ phat,
    const float* __restrict__ w_eb, const float* __restrict__ b_eb,
    const float* __restrict__ w_g,  const float* __restrict__ b_g,
    const float* __restrict__ ln_e_g, const float* __restrict__ ln_e_b,
    const float* __restrict__ w_eo, const float* __restrict__ b_eo,
    const float* __restrict__ effn_g, const float* __restrict__ effn_b,
    const float* __restrict__ w_e1, const float* __restrict__ b_e1,
    const float* __restrict__ w_e2, const float* __restrict__ b_e2)
{
    constexpr int ANORM_B = 512 * 24 * 2;
    constexpr int EB_B    = 512 * 18 * 2;
    constexpr int AUX_B   = (PASS == 1) ? 512 * 18 * 2 : 512 * 24 * 2;
    __shared__ __align__(16) char smem[ANORM_B + EB_B + AUX_B];
    unsigned short* anorm = (unsigned short*)smem;
    unsigned short* eb_l  = (unsigned short*)(smem + ANORM_B);
    unsigned short* aux   = (unsigned short*)(smem + ANORM_B + EB_B);
    unsigned short* tail  = anorm;

    const int bx = blockIdx.x;
    int b, lt, mbase, nchunk;
    if (PASS == 1) { b = bx >> 6; lt = bx & 63; mbase = 0; nchunk = 32; }
    else           { b = bx >> 7; lt = (bx >> 1) & 63; mbase = (bx & 1) * 512; nchunk = 16; }
    const int l0 = lt * 16;
    const int tid = threadIdx.x;
    const int wv = tid >> 6;
    const int lane = tid & 63;
    const int c = lane & 15;
    const int quad = lane >> 4;
    const size_t bN = (size_t)b * 1024;

    const short8 z8 = {0,0,0,0,0,0,0,0};
    const f32x4 zf = {0.f,0.f,0.f,0.f};

    float beb_c = b_eb[c], bg_c = 0.f, be1_c = 0.f, beo_c = 0.f, be2_c = 0.f;
    if constexpr (PASS == 1) bg_c = b_g[c];
    if constexpr (PASS == 2) { be1_c = b_e1[c]; beo_c = b_eo[c]; be2_c = b_e2[c]; }
    for (int e = 0; e < 16; ++e) {
        float lb = ln_e_b[e];
        beb_c += lb * w_eb[e * 16 + c];
        if constexpr (PASS == 1) bg_c += lb * w_g[e * 16 + c];
        if constexpr (PASS == 2) be1_c += effn_b[e] * w_e1[e * 16 + c];
    }
    short8 web_f = z8, wg_f = z8, weo_f = z8, we1_f = z8, we2_f = z8;
    if (quad < 2) {
#pragma unroll
        for (int j = 0; j < 8; ++j) {
            int e = quad * 8 + j;
            web_f[j] = (short)f2bf(ln_e_g[e] * w_eb[e * 16 + c]);
            if constexpr (PASS == 1) wg_f[j] = (short)f2bf(ln_e_g[e] * w_g[e * 16 + c]);
            if constexpr (PASS == 2) {
                weo_f[j] = (short)f2bf(w_eo[e * 16 + c]);
                we1_f[j] = (short)f2bf(effn_g[e] * w_e1[e * 16 + c]);
                we2_f[j] = (short)f2bf(w_e2[e * 16 + c]);
            }
        }
    }
    short8 qf = z8;
    if (quad < 2)
        qf = *(const short8*)(qkvT + (bN + l0 + c) * 768 + wv * 48 + quad * 8);

    float invd[4];
    float den_r[4] = {0.f,0.f,0.f,0.f}, gs_r[4] = {0.f,0.f,0.f,0.f};
    f32x4 acc_pv = zf;
    float muR = 0.f, sgR = 0.f;
    if constexpr (PASS == 2) {
#pragma unroll
        for (int r = 0; r < 4; ++r)
            invd[r] = dbuf[(bN + l0 + quad * 4 + r) * 16 + wv];
    }

    for (int ch = 0; ch < nchunk; ++ch) {
        const int m0 = mbase + ch * 32;
        // ---- stage 1: LN of efeat chunk -> anorm (wave-local rows) ----
        {
            int row = tid >> 1, halfw = tid & 1;
            int lr = row >> 5, mr = row & 31;
            const float* ep = ef_in + ((bN + l0 + lr) * 1024 + m0 + mr) * 16 + halfw * 8;
            float4 x0 = *(const float4*)ep;
            float4 x1 = *(const float4*)(ep + 4);
            float s1 = x0.x + x0.y + x0.z + x0.w + x1.x + x1.y + x1.z + x1.w;
            float s2 = x0.x*x0.x + x0.y*x0.y + x0.z*x0.z + x0.w*x0.w
                     + x1.x*x1.x + x1.y*x1.y + x1.z*x1.z + x1.w*x1.w;
            s1 += __shfl_xor(s1, 1, 64);
            s2 += __shfl_xor(s2, 1, 64);
            float mu = s1 * (1.f / 16.f);
            float vv = s2 * (1.f / 16.f) - mu * mu + 1e-5f;
            float rs = rsqrtf(vv);
            if constexpr (PASS == 2) { muR = mu; sgR = vv * rs; }
            short8 o;
            o[0] = (short)f2bf((x0.x - mu) * rs); o[1] = (short)f2bf((x0.y - mu) * rs);
            o[2] = (short)f2bf((x0.z - mu) * rs); o[3] = (short)f2bf((x0.w - mu) * rs);
            o[4] = (short)f2bf((x1.x - mu) * rs); o[5] = (short)f2bf((x1.y - mu) * rs);
            o[6] = (short)f2bf((x1.z - mu) * rs); o[7] = (short)f2bf((x1.w - mu) * rs);
            *(short8*)(anorm + row * 24 + halfw * 8) = o;
        }
        if constexpr (PASS == 1) {
            // S2 reads only this wave's anorm rows -> same-wave LDS RAW fence
            asm volatile("s_waitcnt lgkmcnt(0)" ::: "memory");
        } else {
            __syncthreads();
        }
        // ---- stage 2: e_bias (+gates) MFMA ----
#pragma unroll
        for (int gg = 0; gg < 2; ++gg) {
            int g = wv * 2 + gg;
            short8 af = z8;
            if (quad < 2) af = *(const short8*)(anorm + (g * 16 + c) * 24 + quad * 8);
            f32x4 eb = __builtin_amdgcn_mfma_f32_16x16x32_bf16(af, web_f, zf, 0, 0, 0);
#pragma unroll
            for (int r = 0; r < 4; ++r)
                eb_l[(g * 16 + quad * 4 + r) * 18 + c] = f2h(eb[r] + beb_c);
            if constexpr (PASS == 1) {
                f32x4 gr = __builtin_amdgcn_mfma_f32_16x16x32_bf16(af, wg_f, zf, 0, 0, 0);
#pragma unroll
                for (int r = 0; r < 4; ++r) {
                    float gv = 1.f / (1.f + __expf(-(gr[r] + bg_c)));
                    aux[(g * 16 + quad * 4 + r) * 18 + c] = f2h(gv);
                }
            }
        }
        __syncthreads();
        // ---- stage 3: QK^T MFMA + softmax numerator ----
        short8 kf0 = z8, kf1 = z8;
        if (quad < 2) {
            kf0 = *(const short8*)(qkvT + (bN + m0 + c) * 768 + wv * 48 + 16 + quad * 8);
            kf1 = *(const short8*)(qkvT + (bN + m0 + 16 + c) * 768 + wv * 48 + 16 + quad * 8);
        }
        f32x4 sq0 = __builtin_amdgcn_mfma_f32_16x16x32_bf16(qf, kf0, zf, 0, 0, 0);
        f32x4 sq1 = __builtin_amdgcn_mfma_f32_16x16x32_bf16(qf, kf1, zf, 0, 0, 0);
#pragma unroll
        for (int k = 0; k < 2; ++k) {
#pragma unroll
            for (int r = 0; r < 4; ++r) {
                float sv = k ? sq1[r] : sq0[r];
                int row = (quad * 4 + r) * 32 + k * 16 + c;
                float s = fminf(fmaxf(sv, -5.f), 5.f) + h2f(eb_l[row * 18 + wv]);
                float pe = exp2f(fmaf(s, L2E, -8.f * L2E));
                if constexpr (PASS == 1) {
                    float gvv = h2f(aux[row * 18 + wv]);
                    den_r[r] += pe;
                    gs_r[r] += gvv;
                    tail[wv * 640 + (quad * 4 + r) * 40 + k * 16 + c] = f2bf(pe * gvv);
                    if (phat)
                        phat[((bN + l0 + quad * 4 + r) * 16 + wv) * 1024
                             + (size_t)(m0 + k * 16 + c)] = f2bf(pe);
                } else {
                    aux[row * 24 + wv] = f2bf(pe * invd[r]);
                }
            }
        }
        // ---- stage 4 ----
        if constexpr (PASS == 1) {
            asm volatile("s_waitcnt lgkmcnt(0)" ::: "memory");
            short8 pa = *(const short8*)(tail + wv * 640 + c * 40 + quad * 8);
            short8 vf = *(const short8*)(vT + (((size_t)(b * 16 + wv) * 16 + c) << 10) + m0 + quad * 8);
            acc_pv = __builtin_amdgcn_mfma_f32_16x16x32_bf16(pa, vf, acc_pv, 0, 0, 0);
        } else {
            __syncthreads();
            const int ar0 = wv * 32 + quad * 4;
            float res0[4], res1[4];
#pragma unroll
            for (int r = 0; r < 4; ++r) {
                int jr = quad * 4 + r;
                float mu0 = __shfl(muR, 2 * jr, 64);
                float sg0 = __shfl(sgR, 2 * jr, 64);
                float mu1 = __shfl(muR, 2 * jr + 32, 64);
                float sg1 = __shfl(sgR, 2 * jr + 32, 64);
                res0[r] = bf2f(anorm[(ar0 + r) * 24 + c]) * sg0 + mu0;
                res1[r] = bf2f(anorm[(ar0 + 16 + r) * 24 + c]) * sg1 + mu1;
            }
            short* t0 = (short*)tail + wv * 768;
            short* t1 = t0 + 384;
            const int g0 = wv * 2, g1 = g0 + 1;
            short8 pf0 = z8, pf1 = z8;
            if (quad < 2) {
                pf0 = *(const short8*)(aux + (g0 * 16 + c) * 24 + quad * 8);
                pf1 = *(const short8*)(aux + (g1 * 16 + c) * 24 + quad * 8);
            }
            f32x4 eo0 = __builtin_amdgcn_mfma_f32_16x16x32_bf16(pf0, weo_f, zf, 0, 0, 0);
            f32x4 eo1 = __builtin_amdgcn_mfma_f32_16x16x32_bf16(pf1, weo_f, zf, 0, 0, 0);
            const size_t gbase = ((bN + l0 + wv) * 1024 + m0 + quad * 4) * 16 + c;
            float ev0[4], ev1[4], hA[4], hB[4];
#pragma unroll
            for (int r = 0; r < 4; ++r) {
                ev0[r] = eo0[r] + beo_c + res0[r];
                ev1[r] = eo1[r] + beo_c + res1[r];
            }
#pragma unroll
            for (int r = 0; r < 4; ++r) {
                float a1 = ev0[r], a2 = ev0[r] * ev0[r];
                float b1v = ev1[r], b2 = ev1[r] * ev1[r];
#pragma unroll
                for (int mm = 1; mm < 16; mm <<= 1) {
                    a1 += __shfl_xor(a1, mm, 64); a2 += __shfl_xor(a2, mm, 64);
                    b1v += __shfl_xor(b1v, mm, 64); b2 += __shfl_xor(b2, mm, 64);
                }
                float muA = a1 * 0.0625f, rsA = rsqrtf(a2 * 0.0625f - muA * muA + 1e-5f);
                float muB = b1v * 0.0625f, rsB = rsqrtf(b2 * 0.0625f - muB * muB + 1e-5f);
                hA[r] = (ev0[r] - muA) * rsA;
                hB[r] = (ev1[r] - muB) * rsB;
            }
#pragma unroll
            for (int r = 0; r < 4; ++r) {
                t0[(quad * 4 + r) * 24 + c] = (short)f2bf(hA[r]);
                t1[(quad * 4 + r) * 24 + c] = (short)f2bf(hB[r]);
            }
            asm volatile("s_waitcnt lgkmcnt(0)" ::: "memory");
            short8 ea0 = z8, ea1 = z8;
            if (quad < 2) {
                ea0 = *(const short8*)(t0 + c * 24 + quad * 8);
                ea1 = *(const short8*)(t1 + c * 24 + quad * 8);
            }
            f32x4 tp0 = __builtin_amdgcn_mfma_f32_16x16x32_bf16(ea0, we1_f, zf, 0, 0, 0);
            f32x4 tp1 = __builtin_amdgcn_mfma_f32_16x16x32_bf16(ea1, we1_f, zf, 0, 0, 0);
#pragma unroll
            for (int r = 0; r < 4; ++r) {
                float x0v = tp0[r] + be1_c;
                float x1v = tp1[r] + be1_c;
                x0v = x0v > 0.f ? x0v : __expf(x0v) - 1.f;
                x1v = x1v > 0.f ? x1v : __expf(x1v) - 1.f;
                t0[(quad * 4 + r) * 24 + c] = (short)f2bf(x0v);
                t1[(quad * 4 + r) * 24 + c] = (short)f2bf(x1v);
            }
            asm volatile("s_waitcnt lgkmcnt(0)" ::: "memory");
            short8 ta0 = z8, ta1 = z8;
            if (quad < 2) {
                ta0 = *(const short8*)(t0 + c * 24 + quad * 8);
                ta1 = *(const short8*)(t1 + c * 24 + quad * 8);
            }
            f32x4 o20 = __builtin_amdgcn_mfma_f32_16x16x32_bf16(ta0, we2_f, zf, 0, 0, 0);
            f32x4 o21 = __builtin_amdgcn_mfma_f32_16x16x32_bf16(ta1, we2_f, zf, 0, 0, 0);
#pragma unroll
            for (int r = 0; r < 4; ++r) {
                ef_out[gbase + r * 16] = ev0[r] + o20[r] + be2_c;
                ef_out[gbase + 256 + r * 16] = ev1[r] + o21[r] + be2_c;
            }
        }
        __syncthreads();
    }

    if constexpr (PASS == 1) {
#pragma unroll
        for (int m = 1; m < 16; m <<= 1) {
#pragma unroll
            for (int r = 0; r < 4; ++r) {
                den_r[r] += __shfl_xor(den_r[r], m, 64);
                gs_r[r]  += __shfl_xor(gs_r[r], m, 64);
            }
        }
#pragma unroll
        for (int r = 0; r < 4; ++r) {
            float id = 1.f / den_r[r];
            int lg = l0 + quad * 4 + r;
            float sc = (lg == 0) ? 1.f : log1pf(gs_r[r]);
            vattn[(bN + lg) * 256 + c * 16 + wv] = f2bf(acc_pv[r] * id * sc);
            if (c == 0) dbuf[(bN + lg) * 16 + wv] = id;
        }
    }
}

// ---- e-out + edge FFN from materialized pe: barrier-free, 1 wave = 1 row --
__global__ __launch_bounds__(512) void eout_kernel(
    const float* __restrict__ ef_in, float* __restrict__ ef_out,
    const unsigned short* __restrict__ phat, const float* __restrict__ dbuf,
    const float* __restrict__ w_eo, const float* __restrict__ b_eo,
    const float* __restrict__ effn_g, const float* __restrict__ effn_b,
    const float* __restrict__ w_e1, const float* __restrict__ b_e1,
    const float* __restrict__ w_e2, const float* __restrict__ b_e2)
{
    __shared__ __align__(16) short trs[8 * 768];
    __shared__ __align__(16) short pes[8 * 768];   // per wave: [32 m][24]
    const int bx = blockIdx.x;                 // (b<<8)|(lo<<1)|half
    const int b = bx >> 8;
    const int lo = (bx >> 1) & 127;
    const int half = bx & 1;
    const int tid = threadIdx.x;
    const int wv = tid >> 6;                   // 0..7
    const int lane = tid & 63;
    const int c = lane & 15;
    const int quad = lane >> 4;
    const size_t rowl = (size_t)b * 1024 + lo * 8 + wv;

    const short8 z8 = {0,0,0,0,0,0,0,0};
    const f32x4 zf = {0.f,0.f,0.f,0.f};

    float beo_c = b_eo[c], be1_c = b_e1[c], be2_c = b_e2[c];
    for (int e = 0; e < 16; ++e) be1_c += effn_b[e] * w_e1[e * 16 + c];
    short8 weo_f = z8, we1_f = z8, we2_f = z8;
    if (quad < 2) {
#pragma unroll
        for (int j = 0; j < 8; ++j) {
            int e = quad * 8 + j;
            weo_f[j] = (short)f2bf(dbuf[rowl * 16 + e] * w_eo[e * 16 + c]);
            we1_f[j] = (short)f2bf(effn_g[e] * w_e1[e * 16 + c]);
            we2_f[j] = (short)f2bf(w_e2[e * 16 + c]);
        }
    }
    short* t0 = (short*)trs + wv * 768;
    short* t1 = t0 + 384;
    short* pesw = (short*)pes + wv * 768;
    const int hh2 = lane >> 2, mseg = lane & 3;

    for (int ch = 0; ch < 16; ++ch) {
        const int m0 = half * 512 + ch * 32;
        {
            uint4 pv = *(const uint4*)(phat + ((rowl * 16 + hh2) << 10) + m0 + mseg * 8);
            const unsigned short* pw = (const unsigned short*)&pv;
#pragma unroll
            for (int j = 0; j < 8; ++j)
                pesw[(mseg * 8 + j) * 24 + hh2] = (short)pw[j];
        }
        asm volatile("s_waitcnt lgkmcnt(0)" ::: "memory");
        short8 pa0 = z8, pa1 = z8;
        if (quad < 2) {
            pa0 = *(const short8*)(pesw + c * 24 + quad * 8);
            pa1 = *(const short8*)(pesw + (c + 16) * 24 + quad * 8);
        }
        f32x4 eo0 = __builtin_amdgcn_mfma_f32_16x16x32_bf16(pa0, weo_f, zf, 0, 0, 0);
        f32x4 eo1 = __builtin_amdgcn_mfma_f32_16x16x32_bf16(pa1, weo_f, zf, 0, 0, 0);
        const size_t gbase = (rowl * 1024 + m0 + quad * 4) * 16 + c;
        float ev0[4], ev1[4], hA[4], hB[4];
#pragma unroll
        for (int r = 0; r < 4; ++r) {
            ev0[r] = eo0[r] + beo_c + ef_in[gbase + r * 16];
            ev1[r] = eo1[r] + beo_c + ef_in[gbase + 256 + r * 16];
        }
#pragma unroll
        for (int r = 0; r < 4; ++r) {
            float a1 = ev0[r], a2 = ev0[r] * ev0[r];
            float b1v = ev1[r], b2 = ev1[r] * ev1[r];
#pragma unroll
            for (int mm = 1; mm < 16; mm <<= 1) {
                a1 += __shfl_xor(a1, mm, 64); a2 += __shfl_xor(a2, mm, 64);
                b1v += __shfl_xor(b1v, mm, 64); b2 += __shfl_xor(b2, mm, 64);
            }
            float muA = a1 * 0.0625f, rsA = rsqrtf(a2 * 0.0625f - muA * muA + 1e-5f);
            float muB = b1v * 0.0625f, rsB = rsqrtf(b2 * 0.0625f - muB * muB + 1e-5f);
            hA[r] = (ev0[r] - muA) * rsA;
            hB[r] = (ev1[r] - muB) * rsB;
        }
#pragma unroll
        for (int r = 0; r < 4; ++r) {
            t0[(quad * 4 + r) * 24 + c] = (short)f2bf(hA[r]);
            t1[(quad * 4 + r) * 24 + c] = (short)f2bf(hB[r]);
        }
        asm volatile("s_waitcnt lgkmcnt(0)" ::: "memory");
        short8 ea0 = z8, ea1 = z8;
        if (quad < 2) {
            ea0 = *(const short8*)(t0 + c * 24 + quad * 8);
            ea1 = *(const short8*)(t1 + c * 24 + quad * 8);
        }
        f32x4 tp0 = __builtin_amdgcn_mfma_f32_16x16x32_bf16(ea0, we1_f, zf, 0, 0, 0);
        f32x4 tp1 = __builtin_amdgcn_mfma_f32_16x16x32_bf16(ea1, we1_f, zf, 0, 0, 0);
#pragma unroll
        for (int r = 0; r < 4; ++r) {
            float x0v = tp0[r] + be1_c;
            float x1v = tp1[r] + be1_c;
            x0v = x0v > 0.f ? x0v : __expf(x0v) - 1.f;
            x1v = x1v > 0.f ? x1v : __expf(x1v) - 1.f;
            t0[(quad * 4 + r) * 24 + c] = (short)f2bf(x0v);
            t1[(quad * 4 + r) * 24 + c] = (short)f2bf(x1v);
        }
        asm volatile("s_waitcnt lgkmcnt(0)" ::: "memory");
        short8 ta0 = z8, ta1 = z8;
        if (quad < 2) {
            ta0 = *(const short8*)(t0 + c * 24 + quad * 8);
            ta1 = *(const short8*)(t1 + c * 24 + quad * 8);
        }
        f32x4 o20 = __builtin_amdgcn_mfma_f32_16x16x32_bf16(ta0, we2_f, zf, 0, 0, 0);
        f32x4 o21 = __builtin_amdgcn_mfma_f32_16x16x32_bf16(ta1, we2_f, zf, 0, 0, 0);
#pragma unroll
        for (int r = 0; r < 4; ++r) {
            ef_out[gbase + r * 16] = ev0[r] + o20[r] + be2_c;
            ef_out[gbase + 256 + r * 16] = ev1[r] + o21[r] + be2_c;
        }
    }
}

extern "C" void kernel_launch(void* const* d_in, const int* in_sizes, int n_in,
                              void* d_out, int out_size, void* d_ws, size_t ws_size,
                              hipStream_t stream)
{
    const float* nfeat = (const float*)d_in[0];
    const float* efeat = (const float*)d_in[1];
    const float* ln_h_g = (const float*)d_in[2];
    const float* ln_h_b = (const float*)d_in[3];
    const float* ln_e_g = (const float*)d_in[4];
    const float* ln_e_b = (const float*)d_in[5];
    const float* w_eb = (const float*)d_in[6];
    const float* b_eb = (const float*)d_in[7];
    const float* w_g  = (const float*)d_in[8];
    const float* b_g  = (const float*)d_in[9];
    const float* w_qkv = (const float*)d_in[10];
    const float* b_qkv = (const float*)d_in[11];
    const float* w_no = (const float*)d_in[12];
    const float* b_no = (const float*)d_in[13];
    const float* ffn_ln_g = (const float*)d_in[14];
    const float* ffn_ln_b = (const float*)d_in[15];
    const float* w_f1 = (const float*)d_in[16];
    const float* b_f1 = (const float*)d_in[17];
    const float* w_f2 = (const float*)d_in[18];
    const float* b_f2 = (const float*)d_in[19];
    const float* w_eo = (const float*)d_in[20];
    const float* b_eo = (const float*)d_in[21];
    const float* effn_g = (const float*)d_in[22];
    const float* effn_b = (const float*)d_in[23];
    const float* w_e1 = (const float*)d_in[24];
    const float* b_e1 = (const float*)d_in[25];
    const float* w_e2 = (const float*)d_in[26];
    const float* b_e2 = (const float*)d_in[27];

    float* out_n = (float*)d_out;
    float* out_e = out_n + (size_t)1048576;

    char* ws = (char*)d_ws;
    unsigned short* hln  = (unsigned short*)(ws);                     // [0,2)
    unsigned short* qkvb = (unsigned short*)(ws + ((size_t)2 << 20)); // [2,8)
    unsigned short* qkvT = (unsigned short*)(ws + ((size_t)8 << 20)); // [8,14)
    unsigned short* vatt = (unsigned short*)(ws + ((size_t)14 << 20));// [14,16)
    float* hbuf          = (float*)(ws + ((size_t)16 << 20));         // [16,20)
    unsigned short* h2ln = (unsigned short*)(ws + ((size_t)20 << 20));// [20,22)
    unsigned short* tbuf = (unsigned short*)(ws + ((size_t)22 << 20));// [22,26)
    float* nf0           = (float*)(ws + ((size_t)26 << 20));         // [26,30)
    unsigned short* vT   = (unsigned short*)(ws + ((size_t)30 << 20));// [30,32)
    float* dbuf          = (float*)(ws + ((size_t)32 << 20));         // 256 KiB
    const bool use_phat  = ws_size >= ((size_t)169 << 20);
    unsigned short* phat = use_phat ? (unsigned short*)(ws + ((size_t)34 << 20)) : nullptr;

    for (int l = 0; l < 2; ++l) {
        const float* nf_in = l ? nf0 : nfeat;
        const float* ef_in = l ? out_e : efeat;
        float* nf_out = l ? out_n : nf0;

        ln256_kernel<<<dim3(1024), dim3(256), 0, stream>>>(
            nf_in, ln_h_g + l * 256, ln_h_b + l * 256, hln);
        gemm_kernel<4><<<dim3(12, 64), dim3(256), 0, stream>>>(
            hln, w_qkv + l * 196608, b_qkv + l * 768,
            (const float*)nullptr, (float*)nullptr, qkvb, 4096, 256, 768);
        repack_kernel<<<dim3(4096), dim3(256), 0, stream>>>(qkvb, qkvT, vT);
        attn_kernel<1><<<dim3(256), dim3(1024), 0, stream>>>(
            ef_in, (float*)nullptr, qkvT, vT, vatt, dbuf, phat,
            w_eb + l * 256, b_eb + l * 16, w_g + l * 256, b_g + l * 16,
            ln_e_g + l * 16, ln_e_b + l * 16,
            nullptr, nullptr, nullptr, nullptr, nullptr, nullptr, nullptr, nullptr);
        if (use_phat) {
            eout_kernel<<<dim3(1024), dim3(512), 0, stream>>>(
                ef_in, out_e, phat, dbuf,
                w_eo + l * 256, b_eo + l * 16,
                effn_g + l * 16, effn_b + l * 16,
                w_e1 + l * 256, b_e1 + l * 16, w_e2 + l * 256, b_e2 + l * 16);
        } else {
            attn_kernel<2><<<dim3(512), dim3(1024), 0, stream>>>(
                ef_in, out_e, qkvT, (const unsigned short*)nullptr,
                (unsigned short*)nullptr, dbuf, (unsigned short*)nullptr,
                w_eb + l * 256, b_eb + l * 16, nullptr, nullptr,
                ln_e_g + l * 16, ln_e_b + l * 16,
                w_eo + l * 256, b_eo + l * 16,
                effn_g + l * 16, effn_b + l * 16,
                w_e1 + l * 256, b_e1 + l * 16, w_e2 + l * 256, b_e2 + l * 16);
        }
        gemm_kernel<2><<<dim3(4, 64), dim3(256), 0, stream>>>(
            vatt, w_no + l * 65536, b_no + l * 256, nf_in,
            hbuf, (unsigned short*)nullptr, 4096, 256, 256);
        ln256_kernel<<<dim3(1024), dim3(256), 0, stream>>>(
            hbuf, ffn_ln_g + l * 256, ffn_ln_b + l * 256, h2ln);
        gemm_kernel<5><<<dim3(8, 64), dim3(256), 0, stream>>>(
            h2ln, w_f1 + l * 131072, b_f1 + l * 512,
            (const float*)nullptr, (float*)nullptr, tbuf, 4096, 256, 512);
        gemm_kernel<2><<<dim3(4, 64), dim3(256), 0, stream>>>(
            tbuf, w_f2 + l * 131072, b_f2 + l * 256, hbuf,
            nf_out, (unsigned short*)nullptr, 4096, 512, 256);
    }
}

// Round 13
// 764.511 us; speedup vs baseline: 1.3272x; 1.0327x over previous
//
#include <hip/hip_runtime.h>
#include <hip/hip_fp16.h>
#include <hip/hip_bf16.h>

#define B_ 4
#define N_ 1024
#define L2E 1.44269504f

typedef __attribute__((ext_vector_type(8))) short short8;
typedef __attribute__((ext_vector_type(4))) float f32x4;
typedef __attribute__((ext_vector_type(4))) unsigned short us4;

static __device__ __forceinline__ unsigned short f2bf(float x) {
    __hip_bfloat16 b = __float2bfloat16(x);
    union { __hip_bfloat16 b; unsigned short u; } v; v.b = b; return v.u;
}
static __device__ __forceinline__ float bf2f(unsigned short u) {
    union { unsigned x; float f; } v; v.x = (unsigned)u << 16; return v.f;
}
static __device__ __forceinline__ unsigned short f2h(float x) {
    __half h = __float2half(x); return __half_as_ushort(h);
}
static __device__ __forceinline__ float h2f(unsigned short u) {
    return __half2float(__ushort_as_half(u));
}

// ---------------- LayerNorm over 256 (one wave per row), bf16 out ----------
__global__ __launch_bounds__(256) void ln256_kernel(
    const float* __restrict__ x, const float* __restrict__ g,
    const float* __restrict__ bta, unsigned short* __restrict__ out)
{
    int row = blockIdx.x * 4 + (threadIdx.x >> 6);
    int lane = threadIdx.x & 63;
    const float4 v = *(const float4*)(x + (size_t)row * 256 + lane * 4);
    float s1 = v.x + v.y + v.z + v.w;
    float s2 = v.x * v.x + v.y * v.y + v.z * v.z + v.w * v.w;
#pragma unroll
    for (int m = 1; m < 64; m <<= 1) {
        s1 += __shfl_xor(s1, m, 64);
        s2 += __shfl_xor(s2, m, 64);
    }
    float mu = s1 * (1.f / 256.f);
    float var = s2 * (1.f / 256.f) - mu * mu;
    float rs = rsqrtf(var + 1e-5f);
    const float4 gv = *(const float4*)(g + lane * 4);
    const float4 bv = *(const float4*)(bta + lane * 4);
    us4 o;
    o[0] = f2bf((v.x - mu) * rs * gv.x + bv.x);
    o[1] = f2bf((v.y - mu) * rs * gv.y + bv.y);
    o[2] = f2bf((v.z - mu) * rs * gv.z + bv.z);
    o[3] = f2bf((v.w - mu) * rs * gv.w + bv.w);
    *(us4*)(out + (size_t)row * 256 + lane * 4) = o;
}

// ------ repack bf16 qkv [bn][(sd)*16+h] -> qkvT [bn][h][sd], vT [b][h][k][n]
__global__ __launch_bounds__(256) void repack_kernel(
    const unsigned short* __restrict__ qkvb, unsigned short* __restrict__ qkvT,
    unsigned short* __restrict__ vT)
{
    __shared__ unsigned short ld[768];
    int bn = blockIdx.x, t = threadIdx.x;
    const unsigned short* src = qkvb + (size_t)bn * 768;
    ld[t] = src[t]; ld[t + 256] = src[t + 256]; ld[t + 512] = src[t + 512];
    __syncthreads();
    unsigned short* dst = qkvT + (size_t)bn * 768;
#pragma unroll
    for (int i = 0; i < 3; ++i) {
        int o = t + i * 256;
        int h = o / 48, sd = o - h * 48;
        dst[o] = ld[sd * 16 + h];
    }
    int b = bn >> 10, n = bn & 1023;
    int h = t >> 4, k = t & 15;
    vT[(((size_t)(b * 16 + h) * 16 + k) << 10) + n] = ld[(32 + k) * 16 + h];
}

// ---------------- generic bf16 MFMA GEMM, 64x64 tile, BK=32 ----------------
// EPI bits: 1 = ELU, 2 = residual add, 4 = bf16 output
template <int EPI>
__global__ __launch_bounds__(256) void gemm_kernel(
    const unsigned short* __restrict__ A, const float* __restrict__ Bw,
    const float* __restrict__ bias, const float* __restrict__ res,
    float* __restrict__ outf, unsigned short* __restrict__ outh,
    int M, int K, int Nn)
{
    __shared__ __align__(16) short As[64][40];
    __shared__ __align__(16) short Bs[64][40];
    int tid = threadIdx.x;
    int n0 = blockIdx.x * 64, m0 = blockIdx.y * 64;
    int lane = tid & 63, wid = tid >> 6;
    int wm = (wid >> 1) * 32, wn = (wid & 1) * 32;
    int fr = lane & 15, quad = lane >> 4;
    f32x4 acc00 = {0.f,0.f,0.f,0.f}, acc01 = {0.f,0.f,0.f,0.f};
    f32x4 acc10 = {0.f,0.f,0.f,0.f}, acc11 = {0.f,0.f,0.f,0.f};
    int ar = tid >> 2, akc = (tid & 3) * 8;
    int bk = tid >> 3, bnc = (tid & 7) * 8;
    for (int k0 = 0; k0 < K; k0 += 32) {
        *(uint4*)&As[ar][akc] = *(const uint4*)(A + (size_t)(m0 + ar) * K + k0 + akc);
        const float* bp = Bw + (size_t)(k0 + bk) * Nn + n0 + bnc;
        float4 b1 = *(const float4*)bp;
        float4 b2 = *(const float4*)(bp + 4);
        Bs[bnc + 0][bk] = (short)f2bf(b1.x);
        Bs[bnc + 1][bk] = (short)f2bf(b1.y);
        Bs[bnc + 2][bk] = (short)f2bf(b1.z);
        Bs[bnc + 3][bk] = (short)f2bf(b1.w);
        Bs[bnc + 4][bk] = (short)f2bf(b2.x);
        Bs[bnc + 5][bk] = (short)f2bf(b2.y);
        Bs[bnc + 6][bk] = (short)f2bf(b2.z);
        Bs[bnc + 7][bk] = (short)f2bf(b2.w);
        __syncthreads();
        short8 af0 = *(const short8*)&As[wm + fr][quad * 8];
        short8 af1 = *(const short8*)&As[wm + 16 + fr][quad * 8];
        short8 bf0 = *(const short8*)&Bs[wn + fr][quad * 8];
        short8 bf1 = *(const short8*)&Bs[wn + 16 + fr][quad * 8];
        acc00 = __builtin_amdgcn_mfma_f32_16x16x32_bf16(af0, bf0, acc00, 0, 0, 0);
        acc01 = __builtin_amdgcn_mfma_f32_16x16x32_bf16(af0, bf1, acc01, 0, 0, 0);
        acc10 = __builtin_amdgcn_mfma_f32_16x16x32_bf16(af1, bf0, acc10, 0, 0, 0);
        acc11 = __builtin_amdgcn_mfma_f32_16x16x32_bf16(af1, bf1, acc11, 0, 0, 0);
        __syncthreads();
    }
#pragma unroll
    for (int fm = 0; fm < 2; ++fm) {
#pragma unroll
        for (int fn = 0; fn < 2; ++fn) {
            f32x4 a = (fm == 0) ? (fn == 0 ? acc00 : acc01) : (fn == 0 ? acc10 : acc11);
#pragma unroll
            for (int r = 0; r < 4; ++r) {
                int row = m0 + wm + fm * 16 + quad * 4 + r;
                int col = n0 + wn + fn * 16 + fr;
                float v = a[r] + bias[col];
                if (EPI & 2) v += res[(size_t)row * Nn + col];
                if (EPI & 1) v = v > 0.f ? v : __expf(v) - 1.f;
                if (EPI & 4) outh[(size_t)row * Nn + col] = f2bf(v);
                else         outf[(size_t)row * Nn + col] = v;
            }
        }
    }
}

// ------------------ fused edge attention (scores / recompute) --------------
// PASS 1: (b, 16-l tile), full m sweep: den/gs -> vattn,dbuf; pe -> phat
//         [b][l][h][m]. Register-prefetched S1 loads; packed (gate|eb) f16
//         pairs in one u32 LDS word. 2 barriers/chunk.
// PASS 2 (fallback when ws too small): recompute s, e-out + edge FFN
template <int PASS>
__global__ __launch_bounds__(1024, 4) void attn_kernel(
    const float* __restrict__ ef_in, float* __restrict__ ef_out,
    const unsigned short* __restrict__ qkvT, const unsigned short* __restrict__ vT,
    unsigned short* __restrict__ vattn, float* __restrict__ dbuf,
    unsigned short* __restrict__ phat,
    const float* __restrict__ w_eb, const float* __restrict__ b_eb,
    const float* __restrict__ w_g,  const float* __restrict__ b_g,
    const float* __restrict__ ln_e_g, const float* __restrict__ ln_e_b,
    const float* __restrict__ w_eo, const float* __restrict__ b_eo,
    const float* __restrict__ effn_g, const float* __restrict__ effn_b,
    const float* __restrict__ w_e1, const float* __restrict__ b_e1,
    const float* __restrict__ w_e2, const float* __restrict__ b_e2)
{
    constexpr int ANORM_B = 512 * 24 * 2;
    constexpr int EB_B    = 512 * 18 * 2;
    constexpr int SMEM_B  = (PASS == 1) ? (ANORM_B + 512 * 18 * 4)
                                        : (ANORM_B + EB_B + 512 * 24 * 2);
    __shared__ __align__(16) char smem[SMEM_B];
    unsigned short* anorm = (unsigned short*)smem;
    unsigned short* tail  = anorm;
    unsigned int* ebg     = (unsigned int*)(smem + ANORM_B);          // PASS 1
    unsigned short* eb_l  = (unsigned short*)(smem + ANORM_B);        // PASS 2
    unsigned short* aux   = (unsigned short*)(smem + ANORM_B + EB_B); // PASS 2

    const int bx = blockIdx.x;
    int b, lt, mbase, nchunk;
    if (PASS == 1) { b = bx >> 6; lt = bx & 63; mbase = 0; nchunk = 32; }
    else           { b = bx >> 7; lt = (bx >> 1) & 63; mbase = (bx & 1) * 512; nchunk = 16; }
    const int l0 = lt * 16;
    const int tid = threadIdx.x;
    const int wv = tid >> 6;
    const int lane = tid & 63;
    const int c = lane & 15;
    const int quad = lane >> 4;
    const size_t bN = (size_t)b * 1024;

    const short8 z8 = {0,0,0,0,0,0,0,0};
    const f32x4 zf = {0.f,0.f,0.f,0.f};

    float beb_c = b_eb[c], bg_c = 0.f, be1_c = 0.f, beo_c = 0.f, be2_c = 0.f;
    if constexpr (PASS == 1) bg_c = b_g[c];
    if constexpr (PASS == 2) { be1_c = b_e1[c]; beo_c = b_eo[c]; be2_c = b_e2[c]; }
    for (int e = 0; e < 16; ++e) {
        float lb = ln_e_b[e];
        beb_c += lb * w_eb[e * 16 + c];
        if constexpr (PASS == 1) bg_c += lb * w_g[e * 16 + c];
        if constexpr (PASS == 2) be1_c += effn_b[e] * w_e1[e * 16 + c];
    }
    short8 web_f = z8, wg_f = z8, weo_f = z8, we1_f = z8, we2_f = z8;
    if (quad < 2) {
#pragma unroll
        for (int j = 0; j < 8; ++j) {
            int e = quad * 8 + j;
            web_f[j] = (short)f2bf(ln_e_g[e] * w_eb[e * 16 + c]);
            if constexpr (PASS == 1) wg_f[j] = (short)f2bf(ln_e_g[e] * w_g[e * 16 + c]);
            if constexpr (PASS == 2) {
                weo_f[j] = (short)f2bf(w_eo[e * 16 + c]);
                we1_f[j] = (short)f2bf(effn_g[e] * w_e1[e * 16 + c]);
                we2_f[j] = (short)f2bf(w_e2[e * 16 + c]);
            }
        }
    }
    short8 qf = z8;
    if (quad < 2)
        qf = *(const short8*)(qkvT + (bN + l0 + c) * 768 + wv * 48 + quad * 8);

    float invd[4];
    float den_r[4] = {0.f,0.f,0.f,0.f}, gs_r[4] = {0.f,0.f,0.f,0.f};
    f32x4 acc_pv = zf;
    float muR = 0.f, sgR = 0.f;
    if constexpr (PASS == 2) {
#pragma unroll
        for (int r = 0; r < 4; ++r)
            invd[r] = dbuf[(bN + l0 + quad * 4 + r) * 16 + wv];
    }

    // stage-1 addressing (row = tid>>1 is wave-local by construction)
    const int s1row = tid >> 1, s1half = tid & 1;
    const float* eprow = ef_in
        + ((bN + l0 + (s1row >> 5)) * 1024 + (s1row & 31)) * 16 + s1half * 8;
    float4 x0, x1;
    if constexpr (PASS == 1) {
        x0 = *(const float4*)(eprow + (size_t)mbase * 16);
        x1 = *(const float4*)(eprow + (size_t)mbase * 16 + 4);
    }

    for (int ch = 0; ch < nchunk; ++ch) {
        const int m0 = mbase + ch * 32;
        float4 x0n, x1n;
        // ---- stage 1: LN of efeat chunk -> anorm (wave-local rows) ----
        if constexpr (PASS == 1) {
            float s1 = x0.x + x0.y + x0.z + x0.w + x1.x + x1.y + x1.z + x1.w;
            float s2 = x0.x*x0.x + x0.y*x0.y + x0.z*x0.z + x0.w*x0.w
                     + x1.x*x1.x + x1.y*x1.y + x1.z*x1.z + x1.w*x1.w;
            s1 += __shfl_xor(s1, 1, 64);
            s2 += __shfl_xor(s2, 1, 64);
            float mu = s1 * (1.f / 16.f);
            float vv = s2 * (1.f / 16.f) - mu * mu + 1e-5f;
            float rs = rsqrtf(vv);
            short8 o;
            o[0] = (short)f2bf((x0.x - mu) * rs); o[1] = (short)f2bf((x0.y - mu) * rs);
            o[2] = (short)f2bf((x0.z - mu) * rs); o[3] = (short)f2bf((x0.w - mu) * rs);
            o[4] = (short)f2bf((x1.x - mu) * rs); o[5] = (short)f2bf((x1.y - mu) * rs);
            o[6] = (short)f2bf((x1.z - mu) * rs); o[7] = (short)f2bf((x1.w - mu) * rs);
            *(short8*)(anorm + s1row * 24 + s1half * 8) = o;
            // prefetch next chunk's efeat block (rides in VGPRs across the chunk)
            int mn = (ch + 1 < nchunk) ? m0 + 32 : m0;
            x0n = *(const float4*)(eprow + (size_t)mn * 16);
            x1n = *(const float4*)(eprow + (size_t)mn * 16 + 4);
            // S2 reads only this wave's anorm rows -> same-wave LDS RAW fence
            asm volatile("s_waitcnt lgkmcnt(0)" ::: "memory");
        } else {
            const float* ep = eprow + (size_t)m0 * 16;
            float4 y0 = *(const float4*)ep;
            float4 y1 = *(const float4*)(ep + 4);
            float s1 = y0.x + y0.y + y0.z + y0.w + y1.x + y1.y + y1.z + y1.w;
            float s2 = y0.x*y0.x + y0.y*y0.y + y0.z*y0.z + y0.w*y0.w
                     + y1.x*y1.x + y1.y*y1.y + y1.z*y1.z + y1.w*y1.w;
            s1 += __shfl_xor(s1, 1, 64);
            s2 += __shfl_xor(s2, 1, 64);
            float mu = s1 * (1.f / 16.f);
            float vv = s2 * (1.f / 16.f) - mu * mu + 1e-5f;
            float rs = rsqrtf(vv);
            muR = mu; sgR = vv * rs;
            short8 o;
            o[0] = (short)f2bf((y0.x - mu) * rs); o[1] = (short)f2bf((y0.y - mu) * rs);
            o[2] = (short)f2bf((y0.z - mu) * rs); o[3] = (short)f2bf((y0.w - mu) * rs);
            o[4] = (short)f2bf((y1.x - mu) * rs); o[5] = (short)f2bf((y1.y - mu) * rs);
            o[6] = (short)f2bf((y1.z - mu) * rs); o[7] = (short)f2bf((y1.w - mu) * rs);
            *(short8*)(anorm + s1row * 24 + s1half * 8) = o;
            __syncthreads();
        }
        // ---- stage 2: e_bias (+gates) MFMA ----
#pragma unroll
        for (int gg = 0; gg < 2; ++gg) {
            int g = wv * 2 + gg;
            short8 af = z8;
            if (quad < 2) af = *(const short8*)(anorm + (g * 16 + c) * 24 + quad * 8);
            f32x4 eb = __builtin_amdgcn_mfma_f32_16x16x32_bf16(af, web_f, zf, 0, 0, 0);
            if constexpr (PASS == 1) {
                f32x4 gr = __builtin_amdgcn_mfma_f32_16x16x32_bf16(af, wg_f, zf, 0, 0, 0);
#pragma unroll
                for (int r = 0; r < 4; ++r) {
                    float gv = 1.f / (1.f + __expf(-(gr[r] + bg_c)));
                    ebg[(g * 16 + quad * 4 + r) * 18 + c] =
                        ((unsigned)f2h(gv) << 16) | (unsigned)f2h(eb[r] + beb_c);
                }
            } else {
#pragma unroll
                for (int r = 0; r < 4; ++r)
                    eb_l[(g * 16 + quad * 4 + r) * 18 + c] = f2h(eb[r] + beb_c);
            }
        }
        __syncthreads();
        // ---- stage 3: QK^T MFMA + softmax numerator ----
        short8 kf0 = z8, kf1 = z8;
        if (quad < 2) {
            kf0 = *(const short8*)(qkvT + (bN + m0 + c) * 768 + wv * 48 + 16 + quad * 8);
            kf1 = *(const short8*)(qkvT + (bN + m0 + 16 + c) * 768 + wv * 48 + 16 + quad * 8);
        }
        f32x4 sq0 = __builtin_amdgcn_mfma_f32_16x16x32_bf16(qf, kf0, zf, 0, 0, 0);
        f32x4 sq1 = __builtin_amdgcn_mfma_f32_16x16x32_bf16(qf, kf1, zf, 0, 0, 0);
#pragma unroll
        for (int k = 0; k < 2; ++k) {
#pragma unroll
            for (int r = 0; r < 4; ++r) {
                float sv = k ? sq1[r] : sq0[r];
                int row = (quad * 4 + r) * 32 + k * 16 + c;
                if constexpr (PASS == 1) {
                    unsigned eg = ebg[row * 18 + wv];
                    float s = fminf(fmaxf(sv, -5.f), 5.f) + h2f((unsigned short)eg);
                    float pe = exp2f(fmaf(s, L2E, -8.f * L2E));
                    float gvv = h2f((unsigned short)(eg >> 16));
                    den_r[r] += pe;
                    gs_r[r] += gvv;
                    tail[wv * 640 + (quad * 4 + r) * 40 + k * 16 + c] = f2bf(pe * gvv);
                    if (phat)
                        phat[((bN + l0 + quad * 4 + r) * 16 + wv) * 1024
                             + (size_t)(m0 + k * 16 + c)] = f2bf(pe);
                } else {
                    float s = fminf(fmaxf(sv, -5.f), 5.f) + h2f(eb_l[row * 18 + wv]);
                    float pe = exp2f(fmaf(s, L2E, -8.f * L2E));
                    aux[row * 24 + wv] = f2bf(pe * invd[r]);
                }
            }
        }
        // ---- stage 4 ----
        if constexpr (PASS == 1) {
            asm volatile("s_waitcnt lgkmcnt(0)" ::: "memory");
            short8 pa = *(const short8*)(tail + wv * 640 + c * 40 + quad * 8);
            short8 vf = *(const short8*)(vT + (((size_t)(b * 16 + wv) * 16 + c) << 10) + m0 + quad * 8);
            acc_pv = __builtin_amdgcn_mfma_f32_16x16x32_bf16(pa, vf, acc_pv, 0, 0, 0);
            x0 = x0n; x1 = x1n;
        } else {
            __syncthreads();
            const int ar0 = wv * 32 + quad * 4;
            float res0[4], res1[4];
#pragma unroll
            for (int r = 0; r < 4; ++r) {
                int jr = quad * 4 + r;
                float mu0 = __shfl(muR, 2 * jr, 64);
                float sg0 = __shfl(sgR, 2 * jr, 64);
                float mu1 = __shfl(muR, 2 * jr + 32, 64);
                float sg1 = __shfl(sgR, 2 * jr + 32, 64);
                res0[r] = bf2f(anorm[(ar0 + r) * 24 + c]) * sg0 + mu0;
                res1[r] = bf2f(anorm[(ar0 + 16 + r) * 24 + c]) * sg1 + mu1;
            }
            short* t0 = (short*)tail + wv * 768;
            short* t1 = t0 + 384;
            const int g0 = wv * 2, g1 = g0 + 1;
            short8 pf0 = z8, pf1 = z8;
            if (quad < 2) {
                pf0 = *(const short8*)(aux + (g0 * 16 + c) * 24 + quad * 8);
                pf1 = *(const short8*)(aux + (g1 * 16 + c) * 24 + quad * 8);
            }
            f32x4 eo0 = __builtin_amdgcn_mfma_f32_16x16x32_bf16(pf0, weo_f, zf, 0, 0, 0);
            f32x4 eo1 = __builtin_amdgcn_mfma_f32_16x16x32_bf16(pf1, weo_f, zf, 0, 0, 0);
            const size_t gbase = ((bN + l0 + wv) * 1024 + m0 + quad * 4) * 16 + c;
            float ev0[4], ev1[4], hA[4], hB[4];
#pragma unroll
            for (int r = 0; r < 4; ++r) {
                ev0[r] = eo0[r] + beo_c + res0[r];
                ev1[r] = eo1[r] + beo_c + res1[r];
            }
#pragma unroll
            for (int r = 0; r < 4; ++r) {
                float a1 = ev0[r], a2 = ev0[r] * ev0[r];
                float b1v = ev1[r], b2 = ev1[r] * ev1[r];
#pragma unroll
                for (int mm = 1; mm < 16; mm <<= 1) {
                    a1 += __shfl_xor(a1, mm, 64); a2 += __shfl_xor(a2, mm, 64);
                    b1v += __shfl_xor(b1v, mm, 64); b2 += __shfl_xor(b2, mm, 64);
                }
                float muA = a1 * 0.0625f, rsA = rsqrtf(a2 * 0.0625f - muA * muA + 1e-5f);
                float muB = b1v * 0.0625f, rsB = rsqrtf(b2 * 0.0625f - muB * muB + 1e-5f);
                hA[r] = (ev0[r] - muA) * rsA;
                hB[r] = (ev1[r] - muB) * rsB;
            }
#pragma unroll
            for (int r = 0; r < 4; ++r) {
                t0[(quad * 4 + r) * 24 + c] = (short)f2bf(hA[r]);
                t1[(quad * 4 + r) * 24 + c] = (short)f2bf(hB[r]);
            }
            asm volatile("s_waitcnt lgkmcnt(0)" ::: "memory");
            short8 ea0 = z8, ea1 = z8;
            if (quad < 2) {
                ea0 = *(const short8*)(t0 + c * 24 + quad * 8);
                ea1 = *(const short8*)(t1 + c * 24 + quad * 8);
            }
            f32x4 tp0 = __builtin_amdgcn_mfma_f32_16x16x32_bf16(ea0, we1_f, zf, 0, 0, 0);
            f32x4 tp1 = __builtin_amdgcn_mfma_f32_16x16x32_bf16(ea1, we1_f, zf, 0, 0, 0);
#pragma unroll
            for (int r = 0; r < 4; ++r) {
                float x0v = tp0[r] + be1_c;
                float x1v = tp1[r] + be1_c;
                x0v = x0v > 0.f ? x0v : __expf(x0v) - 1.f;
                x1v = x1v > 0.f ? x1v : __expf(x1v) - 1.f;
                t0[(quad * 4 + r) * 24 + c] = (short)f2bf(x0v);
                t1[(quad * 4 + r) * 24 + c] = (short)f2bf(x1v);
            }
            asm volatile("s_waitcnt lgkmcnt(0)" ::: "memory");
            short8 ta0 = z8, ta1 = z8;
            if (quad < 2) {
                ta0 = *(const short8*)(t0 + c * 24 + quad * 8);
                ta1 = *(const short8*)(t1 + c * 24 + quad * 8);
            }
            f32x4 o20 = __builtin_amdgcn_mfma_f32_16x16x32_bf16(ta0, we2_f, zf, 0, 0, 0);
            f32x4 o21 = __builtin_amdgcn_mfma_f32_16x16x32_bf16(ta1, we2_f, zf, 0, 0, 0);
#pragma unroll
            for (int r = 0; r < 4; ++r) {
                ef_out[gbase + r * 16] = ev0[r] + o20[r] + be2_c;
                ef_out[gbase + 256 + r * 16] = ev1[r] + o21[r] + be2_c;
            }
        }
        __syncthreads();
    }

    if constexpr (PASS == 1) {
#pragma unroll
        for (int m = 1; m < 16; m <<= 1) {
#pragma unroll
            for (int r = 0; r < 4; ++r) {
                den_r[r] += __shfl_xor(den_r[r], m, 64);
                gs_r[r]  += __shfl_xor(gs_r[r], m, 64);
            }
        }
#pragma unroll
        for (int r = 0; r < 4; ++r) {
            float id = 1.f / den_r[r];
            int lg = l0 + quad * 4 + r;
            float sc = (lg == 0) ? 1.f : log1pf(gs_r[r]);
            vattn[(bN + lg) * 256 + c * 16 + wv] = f2bf(acc_pv[r] * id * sc);
            if (c == 0) dbuf[(bN + lg) * 16 + wv] = id;
        }
    }
}

// ---- e-out + edge FFN from materialized pe: barrier-free, 1 wave = 1 row --
__global__ __launch_bounds__(512) void eout_kernel(
    const float* __restrict__ ef_in, float* __restrict__ ef_out,
    const unsigned short* __restrict__ phat, const float* __restrict__ dbuf,
    const float* __restrict__ w_eo, const float* __restrict__ b_eo,
    const float* __restrict__ effn_g, const float* __restrict__ effn_b,
    const float* __restrict__ w_e1, const float* __restrict__ b_e1,
    const float* __restrict__ w_e2, const float* __restrict__ b_e2)
{
    __shared__ __align__(16) short trs[8 * 768];
    __shared__ __align__(16) short pes[8 * 768];   // per wave: [32 m][24]
    const int bx = blockIdx.x;                 // (b<<8)|(lo<<1)|half
    const int b = bx >> 8;
    const int lo = (bx >> 1) & 127;
    const int half = bx & 1;
    const int tid = threadIdx.x;
    const int wv = tid >> 6;                   // 0..7
    const int lane = tid & 63;
    const int c = lane & 15;
    const int quad = lane >> 4;
    const size_t rowl = (size_t)b * 1024 + lo * 8 + wv;

    const short8 z8 = {0,0,0,0,0,0,0,0};
    const f32x4 zf = {0.f,0.f,0.f,0.f};

    float beo_c = b_eo[c], be1_c = b_e1[c], be2_c = b_e2[c];
    for (int e = 0; e < 16; ++e) be1_c += effn_b[e] * w_e1[e * 16 + c];
    short8 weo_f = z8, we1_f = z8, we2_f = z8;
    if (quad < 2) {
#pragma unroll
        for (int j = 0; j < 8; ++j) {
            int e = quad * 8 + j;
            weo_f[j] = (short)f2bf(dbuf[rowl * 16 + e] * w_eo[e * 16 + c]);
            we1_f[j] = (short)f2bf(effn_g[e] * w_e1[e * 16 + c]);
            we2_f[j] = (short)f2bf(w_e2[e * 16 + c]);
        }
    }
    short* t0 = (short*)trs + wv * 768;
    short* t1 = t0 + 384;
    short* pesw = (short*)pes + wv * 768;
    const int hh2 = lane >> 2, mseg = lane & 3;

    for (int ch = 0; ch < 16; ++ch) {
        const int m0 = half * 512 + ch * 32;
        {
            uint4 pv = *(const uint4*)(phat + ((rowl * 16 + hh2) << 10) + m0 + mseg * 8);
            const unsigned short* pw = (const unsigned short*)&pv;
#pragma unroll
            for (int j = 0; j < 8; ++j)
                pesw[(mseg * 8 + j) * 24 + hh2] = (short)pw[j];
        }
        asm volatile("s_waitcnt lgkmcnt(0)" ::: "memory");
        short8 pa0 = z8, pa1 = z8;
        if (quad < 2) {
            pa0 = *(const short8*)(pesw + c * 24 + quad * 8);
            pa1 = *(const short8*)(pesw + (c + 16) * 24 + quad * 8);
        }
        f32x4 eo0 = __builtin_amdgcn_mfma_f32_16x16x32_bf16(pa0, weo_f, zf, 0, 0, 0);
        f32x4 eo1 = __builtin_amdgcn_mfma_f32_16x16x32_bf16(pa1, weo_f, zf, 0, 0, 0);
        const size_t gbase = (rowl * 1024 + m0 + quad * 4) * 16 + c;
        float ev0[4], ev1[4], hA[4], hB[4];
#pragma unroll
        for (int r = 0; r < 4; ++r) {
            ev0[r] = eo0[r] + beo_c + ef_in[gbase + r * 16];
            ev1[r] = eo1[r] + beo_c + ef_in[gbase + 256 + r * 16];
        }
#pragma unroll
        for (int r = 0; r < 4; ++r) {
            float a1 = ev0[r], a2 = ev0[r] * ev0[r];
            float b1v = ev1[r], b2 = ev1[r] * ev1[r];
#pragma unroll
            for (int mm = 1; mm < 16; mm <<= 1) {
                a1 += __shfl_xor(a1, mm, 64); a2 += __shfl_xor(a2, mm, 64);
                b1v += __shfl_xor(b1v, mm, 64); b2 += __shfl_xor(b2, mm, 64);
            }
            float muA = a1 * 0.0625f, rsA = rsqrtf(a2 * 0.0625f - muA * muA + 1e-5f);
            float muB = b1v * 0.0625f, rsB = rsqrtf(b2 * 0.0625f - muB * muB + 1e-5f);
            hA[r] = (ev0[r] - muA) * rsA;
            hB[r] = (ev1[r] - muB) * rsB;
        }
#pragma unroll
        for (int r = 0; r < 4; ++r) {
            t0[(quad * 4 + r) * 24 + c] = (short)f2bf(hA[r]);
            t1[(quad * 4 + r) * 24 + c] = (short)f2bf(hB[r]);
        }
        asm volatile("s_waitcnt lgkmcnt(0)" ::: "memory");
        short8 ea0 = z8, ea1 = z8;
        if (quad < 2) {
            ea0 = *(const short8*)(t0 + c * 24 + quad * 8);
            ea1 = *(const short8*)(t1 + c * 24 + quad * 8);
        }
        f32x4 tp0 = __builtin_amdgcn_mfma_f32_16x16x32_bf16(ea0, we1_f, zf, 0, 0, 0);
        f32x4 tp1 = __builtin_amdgcn_mfma_f32_16x16x32_bf16(ea1, we1_f, zf, 0, 0, 0);
#pragma unroll
        for (int r = 0; r < 4; ++r) {
            float x0v = tp0[r] + be1_c;
            float x1v = tp1[r] + be1_c;
            x0v = x0v > 0.f ? x0v : __expf(x0v) - 1.f;
            x1v = x1v > 0.f ? x1v : __expf(x1v) - 1.f;
            t0[(quad * 4 + r) * 24 + c] = (short)f2bf(x0v);
            t1[(quad * 4 + r) * 24 + c] = (short)f2bf(x1v);
        }
        asm volatile("s_waitcnt lgkmcnt(0)" ::: "memory");
        short8 ta0 = z8, ta1 = z8;
        if (quad < 2) {
            ta0 = *(const short8*)(t0 + c * 24 + quad * 8);
            ta1 = *(const short8*)(t1 + c * 24 + quad * 8);
        }
        f32x4 o20 = __builtin_amdgcn_mfma_f32_16x16x32_bf16(ta0, we2_f, zf, 0, 0, 0);
        f32x4 o21 = __builtin_amdgcn_mfma_f32_16x16x32_bf16(ta1, we2_f, zf, 0, 0, 0);
#pragma unroll
        for (int r = 0; r < 4; ++r) {
            ef_out[gbase + r * 16] = ev0[r] + o20[r] + be2_c;
            ef_out[gbase + 256 + r * 16] = ev1[r] + o21[r] + be2_c;
        }
    }
}

extern "C" void kernel_launch(void* const* d_in, const int* in_sizes, int n_in,
                              void* d_out, int out_size, void* d_ws, size_t ws_size,
                              hipStream_t stream)
{
    const float* nfeat = (const float*)d_in[0];
    const float* efeat = (const float*)d_in[1];
    const float* ln_h_g = (const float*)d_in[2];
    const float* ln_h_b = (const float*)d_in[3];
    const float* ln_e_g = (const float*)d_in[4];
    const float* ln_e_b = (const float*)d_in[5];
    const float* w_eb = (const float*)d_in[6];
    const float* b_eb = (const float*)d_in[7];
    const float* w_g  = (const float*)d_in[8];
    const float* b_g  = (const float*)d_in[9];
    const float* w_qkv = (const float*)d_in[10];
    const float* b_qkv = (const float*)d_in[11];
    const float* w_no = (const float*)d_in[12];
    const float* b_no = (const float*)d_in[13];
    const float* ffn_ln_g = (const float*)d_in[14];
    const float* ffn_ln_b = (const float*)d_in[15];
    const float* w_f1 = (const float*)d_in[16];
    const float* b_f1 = (const float*)d_in[17];
    const float* w_f2 = (const float*)d_in[18];
    const float* b_f2 = (const float*)d_in[19];
    const float* w_eo = (const float*)d_in[20];
    const float* b_eo = (const float*)d_in[21];
    const float* effn_g = (const float*)d_in[22];
    const float* effn_b = (const float*)d_in[23];
    const float* w_e1 = (const float*)d_in[24];
    const float* b_e1 = (const float*)d_in[25];
    const float* w_e2 = (const float*)d_in[26];
    const float* b_e2 = (const float*)d_in[27];

    float* out_n = (float*)d_out;
    float* out_e = out_n + (size_t)1048576;

    char* ws = (char*)d_ws;
    unsigned short* hln  = (unsigned short*)(ws);                     // [0,2)
    unsigned short* qkvb = (unsigned short*)(ws + ((size_t)2 << 20)); // [2,8)
    unsigned short* qkvT = (unsigned short*)(ws + ((size_t)8 << 20)); // [8,14)
    unsigned short* vatt = (unsigned short*)(ws + ((size_t)14 << 20));// [14,16)
    float* hbuf          = (float*)(ws + ((size_t)16 << 20));         // [16,20)
    unsigned short* h2ln = (unsigned short*)(ws + ((size_t)20 << 20));// [20,22)
    unsigned short* tbuf = (unsigned short*)(ws + ((size_t)22 << 20));// [22,26)
    float* nf0           = (float*)(ws + ((size_t)26 << 20));         // [26,30)
    unsigned short* vT   = (unsigned short*)(ws + ((size_t)30 << 20));// [30,32)
    float* dbuf          = (float*)(ws + ((size_t)32 << 20));         // 256 KiB
    const bool use_phat  = ws_size >= ((size_t)169 << 20);
    unsigned short* phat = use_phat ? (unsigned short*)(ws + ((size_t)34 << 20)) : nullptr;

    for (int l = 0; l < 2; ++l) {
        const float* nf_in = l ? nf0 : nfeat;
        const float* ef_in = l ? out_e : efeat;
        float* nf_out = l ? out_n : nf0;

        ln256_kernel<<<dim3(1024), dim3(256), 0, stream>>>(
            nf_in, ln_h_g + l * 256, ln_h_b + l * 256, hln);
        gemm_kernel<4><<<dim3(12, 64), dim3(256), 0, stream>>>(
            hln, w_qkv + l * 196608, b_qkv + l * 768,
            (const float*)nullptr, (float*)nullptr, qkvb, 4096, 256, 768);
        repack_kernel<<<dim3(4096), dim3(256), 0, stream>>>(qkvb, qkvT, vT);
        attn_kernel<1><<<dim3(256), dim3(1024), 0, stream>>>(
            ef_in, (float*)nullptr, qkvT, vT, vatt, dbuf, phat,
            w_eb + l * 256, b_eb + l * 16, w_g + l * 256, b_g + l * 16,
            ln_e_g + l * 16, ln_e_b + l * 16,
            nullptr, nullptr, nullptr, nullptr, nullptr, nullptr, nullptr, nullptr);
        if (use_phat) {
            eout_kernel<<<dim3(1024), dim3(512), 0, stream>>>(
                ef_in, out_e, phat, dbuf,
                w_eo + l * 256, b_eo + l * 16,
                effn_g + l * 16, effn_b + l * 16,
                w_e1 + l * 256, b_e1 + l * 16, w_e2 + l * 256, b_e2 + l * 16);
        } else {
            attn_kernel<2><<<dim3(512), dim3(1024), 0, stream>>>(
                ef_in, out_e, qkvT, (const unsigned short*)nullptr,
                (unsigned short*)nullptr, dbuf, (unsigned short*)nullptr,
                w_eb + l * 256, b_eb + l * 16, nullptr, nullptr,
                ln_e_g + l * 16, ln_e_b + l * 16,
                w_eo + l * 256, b_eo + l * 16,
                effn_g + l * 16, effn_b + l * 16,
                w_e1 + l * 256, b_e1 + l * 16, w_e2 + l * 256, b_e2 + l * 16);
        }
        gemm_kernel<2><<<dim3(4, 64), dim3(256), 0, stream>>>(
            vatt, w_no + l * 65536, b_no + l * 256, nf_in,
            hbuf, (unsigned short*)nullptr, 4096, 256, 256);
        ln256_kernel<<<dim3(1024), dim3(256), 0, stream>>>(
            hbuf, ffn_ln_g + l * 256, ffn_ln_b + l * 256, h2ln);
        gemm_kernel<5><<<dim3(8, 64), dim3(256), 0, stream>>>(
            h2ln, w_f1 + l * 131072, b_f1 + l * 512,
            (const float*)nullptr, (float*)nullptr, tbuf, 4096, 256, 512);
        gemm_kernel<2><<<dim3(4, 64), dim3(256), 0, stream>>>(
            tbuf, w_f2 + l * 131072, b_f2 + l * 256, hbuf,
            nf_out, (unsigned short*)nullptr, 4096, 512, 256);
    }
}